// Round 1
// baseline (292.961 us; speedup 1.0000x reference)
//
#include <hip/hip_runtime.h>
#include <hip/hip_fp16.h>
#include <math.h>

#define NEG_SLOPE 0.2f
#define BW 512          // bucket node width
#define BSH 9           // log2(BW)
#define CAP 18432       // per-bucket edge capacity (mean ~16.9K)
#define NB_MAX 256

typedef float f4v __attribute__((ext_vector_type(4)));
typedef float f2v __attribute__((ext_vector_type(2)));
typedef int   i2v __attribute__((ext_vector_type(2)));

__device__ __forceinline__ float lrelu(float v) {
    return v > 0.0f ? v : NEG_SLOPE * v;
}
__device__ __forceinline__ float pack2h(float a, float b) {
    __half2 h = __floats2half2_rn(a, b);
    return *reinterpret_cast<float*>(&h);
}
__device__ __forceinline__ float2 unpack2h(float f) {
    __half2 h = *reinterpret_cast<__half2*>(&f);
    return __half22float2(h);
}
__device__ __forceinline__ void nt_store4(float4 v, float4* p) {
    f4v x = {v.x, v.y, v.z, v.w};
    __builtin_nontemporal_store(x, (f4v*)p);
}

// ---------------- K1: node projection (+ zero bucket cursors).
// ga[i]={as01h,as23h,x0,x1}; spack[i]={as01h,as23h, as2(later), 0};
// dpack[i] low float2 = {ad01h, ad23h} (rs half written by l1_gather).
__global__ __launch_bounds__(256) void k_l1_node(
    const float* __restrict__ x, const float* __restrict__ W1,
    const float* __restrict__ asw, const float* __restrict__ adw,
    float4* __restrict__ ga, float4* __restrict__ spack,
    float2* __restrict__ dpack2, int* __restrict__ bucketCursor,
    int nb, int n)
{
    int i = blockIdx.x * blockDim.x + threadIdx.x;
    if (i < nb) bucketCursor[i] = 0;
    if (i >= n) return;
    float2 xv = ((const float2*)x)[i];
    float as[4] = {0.f, 0.f, 0.f, 0.f};
    float ad[4] = {0.f, 0.f, 0.f, 0.f};
    #pragma unroll
    for (int j = 0; j < 32; ++j) {
        float h = xv.x * W1[j] + xv.y * W1[32 + j];
        as[j >> 3] += h * asw[j];
        ad[j >> 3] += h * adw[j];
    }
    float p01 = pack2h(as[0], as[1]), p23 = pack2h(as[2], as[3]);
    ga[i] = make_float4(p01, p23, xv.x, xv.y);
    spack[i] = make_float4(p01, p23, 0.f, 0.f);
    dpack2[2 * i] = make_float2(pack2h(ad[0], ad[1]), pack2h(ad[2], ad[3]));
}

// ---------------- KA: LDS-binned bucket scatter (4096 edges/block).
// Per staged slot also records its bucket (sbk) -> no binary search on drain.
__global__ __launch_bounds__(256) void k_binA(
    const int* __restrict__ ei, int* __restrict__ bucketCursor,
    unsigned int* __restrict__ binned, int E, int Et, int nb)
{
    __shared__ int cnt[NB_MAX], lscan[NB_MAX], base[NB_MAX], lcur[NB_MAX];
    __shared__ unsigned int staging[4096];
    __shared__ short sbk[4096];
    int t = threadIdx.x;
    int c0 = blockIdx.x * 4096;
    unsigned int ent[16];
    short bb[16];
    #pragma unroll
    for (int k = 0; k < 16; ++k) {
        int e = c0 + k * 256 + t;
        int s, d;
        if (e < E) {
            s = __builtin_nontemporal_load(&ei[e]);
            d = __builtin_nontemporal_load(&ei[E + e]);
        } else { s = e - E; d = s; }
        bool valid = e < Et;
        bb[k] = valid ? (short)(d >> BSH) : (short)(-1);
        ent[k] = ((unsigned int)s << BSH) | (unsigned int)(d & (BW - 1));
    }
    cnt[t] = 0;
    __syncthreads();
    #pragma unroll
    for (int k = 0; k < 16; ++k)
        if (bb[k] >= 0) atomicAdd(&cnt[bb[k]], 1);
    __syncthreads();
    int c = cnt[t];
    lscan[t] = c;
    __syncthreads();
    // parallel inclusive scan over 256 entries
    for (int off = 1; off < 256; off <<= 1) {
        int v = (t >= off) ? lscan[t - off] : 0;
        __syncthreads();
        lscan[t] += v;
        __syncthreads();
    }
    int tot = lscan[255];
    int ex = lscan[t] - c;
    __syncthreads();
    lscan[t] = ex;          // chunk-local exclusive start of bucket t
    lcur[t] = ex;
    if (t < nb && c > 0) base[t] = atomicAdd(&bucketCursor[t], c);
    __syncthreads();
    #pragma unroll
    for (int k = 0; k < 16; ++k)
        if (bb[k] >= 0) {
            int p = atomicAdd(&lcur[bb[k]], 1);
            staging[p] = ent[k];
            sbk[p] = bb[k];
        }
    __syncthreads();
    for (int j = t; j < tot; j += 256) {
        int lo = sbk[j];
        __builtin_nontemporal_store(staging[j],
            &binned[(size_t)lo * CAP + base[lo] + (j - lscan[lo])]);
    }
}

// ---------------- KB: per-bucket counting sort -> CSR (1024 threads).
__global__ __launch_bounds__(1024) void k_binB(
    const unsigned int* __restrict__ binned, const int* __restrict__ bucketCursor,
    int* __restrict__ sorted, int2* __restrict__ rowrange, int n, int nb)
{
    __shared__ int cnt[BW], cur[BW];
    int t = threadIdx.x;
    int b = blockIdx.x;
    int m = bucketCursor[b];
    size_t base = (size_t)b * CAP;
    int node0 = b << BSH;
    if (t < BW) cnt[t] = 0;
    __syncthreads();
    for (int i = t; i < m; i += 1024)
        atomicAdd(&cnt[binned[base + i] & (BW - 1)], 1);
    __syncthreads();
    int deg = (t < BW) ? cnt[t] : 0;
    for (int off = 1; off < BW; off <<= 1) {
        int v = (t >= off && t < BW) ? cnt[t - off] : 0;
        __syncthreads();
        if (t < BW) cnt[t] += v;
        __syncthreads();
    }
    if (t < BW) {
        int ex = cnt[t] - deg;
        cur[t] = ex;
        int node = node0 + t;
        if (node < n)
            rowrange[node] = make_int2((int)base + ex, (int)base + ex + deg);
    }
    __syncthreads();
    for (int i = t; i < m; i += 1024) {
        unsigned int en = binned[base + i];
        int dl = (int)(en & (BW - 1));
        int p = atomicAdd(&cur[dl], 1);
        sorted[base + p] = (int)(en >> BSH);
    }
}

// ---------------- K5: CSR layer-1 gather, 2 lanes per dst row + L2 prep.
__global__ __launch_bounds__(256) void k_l1_gather(
    const int2* __restrict__ rowrange, const int* __restrict__ sorted,
    const float4* __restrict__ ga, float2* __restrict__ dpack2,
    const float* __restrict__ W1, const float* __restrict__ b1,
    const float* __restrict__ W2,
    const float* __restrict__ asw2, const float* __restrict__ adw2,
    float4* __restrict__ pk2f, float4* __restrict__ spack,
    __half* __restrict__ dpk2h, int n)
{
    int t = blockIdx.x * blockDim.x + threadIdx.x;
    int d = t >> 1, half = t & 1;
    if (d >= n) return;
    int2 rr = rowrange[d];
    int beg = rr.x, end = rr.y;
    float2 adp = dpack2[2 * d];
    float2 ad01 = unpack2h(adp.x), ad23 = unpack2h(adp.y);
    float see[4] = {0.f, 0.f, 0.f, 0.f};
    float sx0[4] = {0.f, 0.f, 0.f, 0.f};
    float sx1[4] = {0.f, 0.f, 0.f, 0.f};
    int i = beg + half;
    for (; i + 2 < end; i += 4) {
        int s0 = sorted[i], s1 = sorted[i + 2];
        float4 v0 = ga[s0], v1 = ga[s1];
        #pragma unroll
        for (int k = 0; k < 2; ++k) {
            float4 v = k ? v1 : v0;
            float2 a01 = unpack2h(v.x), a23 = unpack2h(v.y);
            float e0 = __expf(lrelu(a01.x + ad01.x));
            float e1 = __expf(lrelu(a01.y + ad01.y));
            float e2 = __expf(lrelu(a23.x + ad23.x));
            float e3 = __expf(lrelu(a23.y + ad23.y));
            see[0] += e0; sx0[0] += e0 * v.z; sx1[0] += e0 * v.w;
            see[1] += e1; sx0[1] += e1 * v.z; sx1[1] += e1 * v.w;
            see[2] += e2; sx0[2] += e2 * v.z; sx1[2] += e2 * v.w;
            see[3] += e3; sx0[3] += e3 * v.z; sx1[3] += e3 * v.w;
        }
    }
    for (; i < end; i += 2) {
        float4 v = ga[sorted[i]];
        float2 a01 = unpack2h(v.x), a23 = unpack2h(v.y);
        float e0 = __expf(lrelu(a01.x + ad01.x));
        float e1 = __expf(lrelu(a01.y + ad01.y));
        float e2 = __expf(lrelu(a23.x + ad23.x));
        float e3 = __expf(lrelu(a23.y + ad23.y));
        see[0] += e0; sx0[0] += e0 * v.z; sx1[0] += e0 * v.w;
        see[1] += e1; sx0[1] += e1 * v.z; sx1[1] += e1 * v.w;
        see[2] += e2; sx0[2] += e2 * v.z; sx1[2] += e2 * v.w;
        see[3] += e3; sx0[3] += e3 * v.z; sx1[3] += e3 * v.w;
    }
    // combine lane pairs
    #pragma unroll
    for (int h = 0; h < 4; ++h) {
        see[h] += __shfl_xor(see[h], 1);
        sx0[h] += __shfl_xor(sx0[h], 1);
        sx1[h] += __shfl_xor(sx1[h], 1);
    }
    if (half) return;
    float rs[4];
    #pragma unroll
    for (int h = 0; h < 4; ++h) rs[h] = 1.0f / (see[h] + 1e-16f);
    dpack2[2 * d + 1] = make_float2(pack2h(rs[0], rs[1]), pack2h(rs[2], rs[3]));
    float h20 = 0.f, h21 = 0.f;
    #pragma unroll
    for (int j = 0; j < 32; ++j) {
        int h = j >> 3;
        float num = W1[j] * sx0[h] + W1[32 + j] * sx1[h];
        float o = num * rs[h] + b1[j];
        float he = o > 0.f ? o : expm1f(o);
        h20 += he * W2[2 * j];
        h21 += he * W2[2 * j + 1];
    }
    float as2 = h20 * asw2[0] + h21 * asw2[1];
    float ad2 = h20 * adw2[0] + h21 * adw2[1];
    pk2f[d] = make_float4(as2, h20, h21, ad2);
    ((float*)&spack[d])[2] = as2;        // spack.z
    dpk2h[2 * d] = __float2half(ad2);    // low half of packed {ad2h, rs2h}
}

// ---------------- K6: CSR layer-2 gather, 2 lanes per dst row + epilogue.
__global__ __launch_bounds__(256) void k_l2_gather(
    const int2* __restrict__ rowrange, const int* __restrict__ sorted,
    const float4* __restrict__ pk2f, const float* __restrict__ b2,
    __half* __restrict__ dpk2h, float* __restrict__ out, int n)
{
    int t = blockIdx.x * blockDim.x + threadIdx.x;
    int d = t >> 1, half = t & 1;
    if (d >= n) return;
    int2 rr = rowrange[d];
    int beg = rr.x, end = rr.y;
    float ad2 = pk2f[d].w;
    float se = 0.f, a0 = 0.f, a1 = 0.f;
    int i = beg + half;
    for (; i + 2 < end; i += 4) {
        int s0 = sorted[i], s1 = sorted[i + 2];
        float4 p0 = pk2f[s0], p1 = pk2f[s1];
        float e0 = __expf(lrelu(p0.x + ad2));
        float e1 = __expf(lrelu(p1.x + ad2));
        se += e0 + e1;
        a0 += e0 * p0.y + e1 * p1.y;
        a1 += e0 * p0.z + e1 * p1.z;
    }
    for (; i < end; i += 2) {
        float4 p = pk2f[sorted[i]];
        float ee = __expf(lrelu(p.x + ad2));
        se += ee; a0 += ee * p.y; a1 += ee * p.z;
    }
    se += __shfl_xor(se, 1);
    a0 += __shfl_xor(a0, 1);
    a1 += __shfl_xor(a1, 1);
    if (half) return;
    float rs2 = 1.0f / (se + 1e-16f);
    dpk2h[2 * d + 1] = __float2half(rs2);  // high half of {ad2h, rs2h}
    ((float2*)out)[d] = make_float2(a0 * rs2 + b2[0], a1 * rs2 + b2[1]);
}

// ---------------- K7: merged COO alpha pass, ONE edge per thread.
// Lane i stores alpha1[e] at byte offset 16*lane -> each nt_store4 instruction
// writes a contiguous 1KB wave segment (full 64B lines, no partial-line
// nontemporal writes). Old 2-edges/thread layout strided lanes by 32B per
// store -> ~1.9x HBM write amplification (WRITE_SIZE 113MB vs 66MB ideal).
__global__ __launch_bounds__(256) void k_alpha(
    const int* __restrict__ ei, const float4* __restrict__ spack,
    const float4* __restrict__ dpack, const float* __restrict__ dpk2hf,
    float4* __restrict__ alpha1, float* __restrict__ alpha2, int E, int Et)
{
    int e = blockIdx.x * blockDim.x + threadIdx.x;
    if (e >= Et) return;
    int s, d;
    if (e < E) {
        s = __builtin_nontemporal_load(&ei[e]);
        d = __builtin_nontemporal_load(&ei[E + e]);
    } else {
        s = e - E; d = s;   // self-loop tail
    }
    float4 sp = spack[s];
    float4 dp = dpack[d];
    float  dh = dpk2hf[d];

    float2 a01 = unpack2h(sp.x), a23 = unpack2h(sp.y);
    float2 b01 = unpack2h(dp.x), b23 = unpack2h(dp.y);
    float2 r01 = unpack2h(dp.z), r23 = unpack2h(dp.w);
    float4 al;
    al.x = __expf(lrelu(a01.x + b01.x)) * r01.x;
    al.y = __expf(lrelu(a01.y + b01.y)) * r01.y;
    al.z = __expf(lrelu(a23.x + b23.x)) * r23.x;
    al.w = __expf(lrelu(a23.y + b23.y)) * r23.y;
    nt_store4(al, &alpha1[e]);

    float2 ar = unpack2h(dh);
    float o2 = __expf(lrelu(sp.z + ar.x)) * ar.y;
    __builtin_nontemporal_store(o2, &alpha2[e]);
}

extern "C" void kernel_launch(void* const* d_in, const int* in_sizes, int n_in,
                              void* d_out, int out_size, void* d_ws, size_t ws_size,
                              hipStream_t stream)
{
    const float* x   = (const float*)d_in[0];
    const int*   ei  = (const int*)d_in[1];
    const float* W1  = (const float*)d_in[3];
    const float* as1 = (const float*)d_in[4];
    const float* ad1 = (const float*)d_in[5];
    const float* b1  = (const float*)d_in[6];
    const float* W2  = (const float*)d_in[7];
    const float* as2 = (const float*)d_in[8];
    const float* ad2 = (const float*)d_in[9];
    const float* b2  = (const float*)d_in[10];

    const int n  = in_sizes[0] / 2;   // 100000
    const int E  = in_sizes[1] / 2;   // 3200000 (even)
    const int Et = E + n;             // even
    const int nb = (n + BW - 1) >> BSH;  // 196

    char* w = (char*)d_ws;
    float4* ga    = (float4*)w;  w += (size_t)n * sizeof(float4);
    float4* spack = (float4*)w;  w += (size_t)n * sizeof(float4);
    float4* dpack = (float4*)w;  w += (size_t)n * sizeof(float4);
    float4* pk2f  = (float4*)w;  w += (size_t)n * sizeof(float4);
    float*  dpk2hf= (float*)w;   w += (size_t)n * sizeof(float);
    int2*   rowrange = (int2*)w; w += (size_t)n * sizeof(int2);
    int*    sorted   = (int*)w;  w += (size_t)nb * CAP * sizeof(int);
    int*    bucketCursor = (int*)w; w += (size_t)nb * sizeof(int);

    float*  out    = (float*)d_out;
    float4* alpha1 = (float4*)(out + (size_t)n * 2);
    float*  alpha2 = (float*)(alpha1 + (size_t)Et);
    // binned scratch lives in the alpha1 output region, overwritten by k_alpha.
    unsigned int* binned = (unsigned int*)alpha1;

    dim3 blk(256);
    int gn   = (n + 255) / 256;
    int gn2  = (2 * n + 255) / 256;
    int gA   = (Et + 4095) / 4096;
    int gE   = (Et + 255) / 256;

    k_l1_node  <<<gn,  blk, 0, stream>>>(x, W1, as1, ad1, ga, spack,
                                         (float2*)dpack, bucketCursor, nb, n);
    k_binA     <<<gA,  blk, 0, stream>>>(ei, bucketCursor, binned, E, Et, nb);
    k_binB     <<<nb, dim3(1024), 0, stream>>>(binned, bucketCursor, sorted, rowrange, n, nb);
    k_l1_gather<<<gn2, blk, 0, stream>>>(rowrange, sorted, ga, (float2*)dpack,
                                         W1, b1, W2, as2, ad2, pk2f, spack,
                                         (__half*)dpk2hf, n);
    k_l2_gather<<<gn2, blk, 0, stream>>>(rowrange, sorted, pk2f, b2,
                                         (__half*)dpk2hf, out, n);
    k_alpha    <<<gE,  blk, 0, stream>>>(ei, spack, dpack, dpk2hf,
                                         alpha1, alpha2, E, Et);
}

// Round 2
// 289.683 us; speedup vs baseline: 1.0113x; 1.0113x over previous
//
#include <hip/hip_runtime.h>
#include <hip/hip_fp16.h>
#include <math.h>

#define NEG_SLOPE 0.2f
#define BW 512          // bucket node width
#define BSH 9           // log2(BW)
#define CAP 18432       // per-bucket edge capacity (mean ~16.9K)
#define NB_MAX 256

typedef float f4v __attribute__((ext_vector_type(4)));
typedef float f2v __attribute__((ext_vector_type(2)));
typedef int   i2v __attribute__((ext_vector_type(2)));

__device__ __forceinline__ float lrelu(float v) {
    return v > 0.0f ? v : NEG_SLOPE * v;
}
__device__ __forceinline__ float pack2h(float a, float b) {
    __half2 h = __floats2half2_rn(a, b);
    return *reinterpret_cast<float*>(&h);
}
__device__ __forceinline__ float2 unpack2h(float f) {
    __half2 h = *reinterpret_cast<__half2*>(&f);
    return __half22float2(h);
}
__device__ __forceinline__ void nt_store4(float4 v, float4* p) {
    f4v x = {v.x, v.y, v.z, v.w};
    __builtin_nontemporal_store(x, (f4v*)p);
}
__device__ __forceinline__ void nt_store2(float2 v, float2* p) {
    f2v x = {v.x, v.y};
    __builtin_nontemporal_store(x, (f2v*)p);
}

// ---------------- K1: node projection (+ zero bucket cursors).
// ga[i]={as01h,as23h,x0,x1}; spack[i]={as01h,as23h, as2(later), 0};
// dpk[2i]={ad01h,ad23h, rs01h,rs23h(later)}; dpk[2i+1]={ad2,rs2(later),-,-}.
// 32B dst record: one 64B-line touch for the whole dst side in k_alpha.
__global__ __launch_bounds__(256) void k_l1_node(
    const float* __restrict__ x, const float* __restrict__ W1,
    const float* __restrict__ asw, const float* __restrict__ adw,
    float4* __restrict__ ga, float4* __restrict__ spack,
    float4* __restrict__ dpk, int* __restrict__ bucketCursor,
    int nb, int n)
{
    int i = blockIdx.x * blockDim.x + threadIdx.x;
    if (i < nb) bucketCursor[i] = 0;
    if (i >= n) return;
    float2 xv = ((const float2*)x)[i];
    float as[4] = {0.f, 0.f, 0.f, 0.f};
    float ad[4] = {0.f, 0.f, 0.f, 0.f};
    #pragma unroll
    for (int j = 0; j < 32; ++j) {
        float h = xv.x * W1[j] + xv.y * W1[32 + j];
        as[j >> 3] += h * asw[j];
        ad[j >> 3] += h * adw[j];
    }
    float p01 = pack2h(as[0], as[1]), p23 = pack2h(as[2], as[3]);
    ga[i] = make_float4(p01, p23, xv.x, xv.y);
    spack[i] = make_float4(p01, p23, 0.f, 0.f);
    dpk[2 * i] = make_float4(pack2h(ad[0], ad[1]), pack2h(ad[2], ad[3]), 0.f, 0.f);
}

// ---------------- KA: LDS-binned bucket scatter (4096 edges/block).
// Per staged slot also records its bucket (sbk) -> no binary search on drain.
__global__ __launch_bounds__(256) void k_binA(
    const int* __restrict__ ei, int* __restrict__ bucketCursor,
    unsigned int* __restrict__ binned, int E, int Et, int nb)
{
    __shared__ int cnt[NB_MAX], lscan[NB_MAX], base[NB_MAX], lcur[NB_MAX];
    __shared__ unsigned int staging[4096];
    __shared__ short sbk[4096];
    int t = threadIdx.x;
    int c0 = blockIdx.x * 4096;
    unsigned int ent[16];
    short bb[16];
    #pragma unroll
    for (int k = 0; k < 16; ++k) {
        int e = c0 + k * 256 + t;
        int s, d;
        if (e < E) {
            s = __builtin_nontemporal_load(&ei[e]);
            d = __builtin_nontemporal_load(&ei[E + e]);
        } else { s = e - E; d = s; }
        bool valid = e < Et;
        bb[k] = valid ? (short)(d >> BSH) : (short)(-1);
        ent[k] = ((unsigned int)s << BSH) | (unsigned int)(d & (BW - 1));
    }
    cnt[t] = 0;
    __syncthreads();
    #pragma unroll
    for (int k = 0; k < 16; ++k)
        if (bb[k] >= 0) atomicAdd(&cnt[bb[k]], 1);
    __syncthreads();
    int c = cnt[t];
    lscan[t] = c;
    __syncthreads();
    // parallel inclusive scan over 256 entries
    for (int off = 1; off < 256; off <<= 1) {
        int v = (t >= off) ? lscan[t - off] : 0;
        __syncthreads();
        lscan[t] += v;
        __syncthreads();
    }
    int tot = lscan[255];
    int ex = lscan[t] - c;
    __syncthreads();
    lscan[t] = ex;          // chunk-local exclusive start of bucket t
    lcur[t] = ex;
    if (t < nb && c > 0) base[t] = atomicAdd(&bucketCursor[t], c);
    __syncthreads();
    #pragma unroll
    for (int k = 0; k < 16; ++k)
        if (bb[k] >= 0) {
            int p = atomicAdd(&lcur[bb[k]], 1);
            staging[p] = ent[k];
            sbk[p] = bb[k];
        }
    __syncthreads();
    for (int j = t; j < tot; j += 256) {
        int lo = sbk[j];
        __builtin_nontemporal_store(staging[j],
            &binned[(size_t)lo * CAP + base[lo] + (j - lscan[lo])]);
    }
}

// ---------------- KB: per-bucket counting sort -> CSR (1024 threads).
__global__ __launch_bounds__(1024) void k_binB(
    const unsigned int* __restrict__ binned, const int* __restrict__ bucketCursor,
    int* __restrict__ sorted, int2* __restrict__ rowrange, int n, int nb)
{
    __shared__ int cnt[BW], cur[BW];
    int t = threadIdx.x;
    int b = blockIdx.x;
    int m = bucketCursor[b];
    size_t base = (size_t)b * CAP;
    int node0 = b << BSH;
    if (t < BW) cnt[t] = 0;
    __syncthreads();
    for (int i = t; i < m; i += 1024)
        atomicAdd(&cnt[binned[base + i] & (BW - 1)], 1);
    __syncthreads();
    int deg = (t < BW) ? cnt[t] : 0;
    for (int off = 1; off < BW; off <<= 1) {
        int v = (t >= off && t < BW) ? cnt[t - off] : 0;
        __syncthreads();
        if (t < BW) cnt[t] += v;
        __syncthreads();
    }
    if (t < BW) {
        int ex = cnt[t] - deg;
        cur[t] = ex;
        int node = node0 + t;
        if (node < n)
            rowrange[node] = make_int2((int)base + ex, (int)base + ex + deg);
    }
    __syncthreads();
    for (int i = t; i < m; i += 1024) {
        unsigned int en = binned[base + i];
        int dl = (int)(en & (BW - 1));
        int p = atomicAdd(&cur[dl], 1);
        sorted[base + p] = (int)(en >> BSH);
    }
}

// ---------------- K5: CSR layer-1 gather, 2 lanes per dst row + L2 prep.
__global__ __launch_bounds__(256) void k_l1_gather(
    const int2* __restrict__ rowrange, const int* __restrict__ sorted,
    const float4* __restrict__ ga, float4* __restrict__ dpk,
    const float* __restrict__ W1, const float* __restrict__ b1,
    const float* __restrict__ W2,
    const float* __restrict__ asw2, const float* __restrict__ adw2,
    float4* __restrict__ pk2f, float4* __restrict__ spack, int n)
{
    int t = blockIdx.x * blockDim.x + threadIdx.x;
    int d = t >> 1, half = t & 1;
    if (d >= n) return;
    int2 rr = rowrange[d];
    int beg = rr.x, end = rr.y;
    float2 adp = *(const float2*)&dpk[2 * d];
    float2 ad01 = unpack2h(adp.x), ad23 = unpack2h(adp.y);
    float see[4] = {0.f, 0.f, 0.f, 0.f};
    float sx0[4] = {0.f, 0.f, 0.f, 0.f};
    float sx1[4] = {0.f, 0.f, 0.f, 0.f};
    int i = beg + half;
    for (; i + 2 < end; i += 4) {
        int s0 = sorted[i], s1 = sorted[i + 2];
        float4 v0 = ga[s0], v1 = ga[s1];
        #pragma unroll
        for (int k = 0; k < 2; ++k) {
            float4 v = k ? v1 : v0;
            float2 a01 = unpack2h(v.x), a23 = unpack2h(v.y);
            float e0 = __expf(lrelu(a01.x + ad01.x));
            float e1 = __expf(lrelu(a01.y + ad01.y));
            float e2 = __expf(lrelu(a23.x + ad23.x));
            float e3 = __expf(lrelu(a23.y + ad23.y));
            see[0] += e0; sx0[0] += e0 * v.z; sx1[0] += e0 * v.w;
            see[1] += e1; sx0[1] += e1 * v.z; sx1[1] += e1 * v.w;
            see[2] += e2; sx0[2] += e2 * v.z; sx1[2] += e2 * v.w;
            see[3] += e3; sx0[3] += e3 * v.z; sx1[3] += e3 * v.w;
        }
    }
    for (; i < end; i += 2) {
        float4 v = ga[sorted[i]];
        float2 a01 = unpack2h(v.x), a23 = unpack2h(v.y);
        float e0 = __expf(lrelu(a01.x + ad01.x));
        float e1 = __expf(lrelu(a01.y + ad01.y));
        float e2 = __expf(lrelu(a23.x + ad23.x));
        float e3 = __expf(lrelu(a23.y + ad23.y));
        see[0] += e0; sx0[0] += e0 * v.z; sx1[0] += e0 * v.w;
        see[1] += e1; sx0[1] += e1 * v.z; sx1[1] += e1 * v.w;
        see[2] += e2; sx0[2] += e2 * v.z; sx1[2] += e2 * v.w;
        see[3] += e3; sx0[3] += e3 * v.z; sx1[3] += e3 * v.w;
    }
    // combine lane pairs
    #pragma unroll
    for (int h = 0; h < 4; ++h) {
        see[h] += __shfl_xor(see[h], 1);
        sx0[h] += __shfl_xor(sx0[h], 1);
        sx1[h] += __shfl_xor(sx1[h], 1);
    }
    if (half) return;
    float rs[4];
    #pragma unroll
    for (int h = 0; h < 4; ++h) rs[h] = 1.0f / (see[h] + 1e-16f);
    ((float2*)&dpk[2 * d])[1] = make_float2(pack2h(rs[0], rs[1]), pack2h(rs[2], rs[3]));
    float h20 = 0.f, h21 = 0.f;
    #pragma unroll
    for (int j = 0; j < 32; ++j) {
        int h = j >> 3;
        float num = W1[j] * sx0[h] + W1[32 + j] * sx1[h];
        float o = num * rs[h] + b1[j];
        float he = o > 0.f ? o : expm1f(o);
        h20 += he * W2[2 * j];
        h21 += he * W2[2 * j + 1];
    }
    float as2 = h20 * asw2[0] + h21 * asw2[1];
    float ad2 = h20 * adw2[0] + h21 * adw2[1];
    pk2f[d] = make_float4(as2, h20, h21, ad2);
    ((float*)&spack[d])[2] = as2;        // spack.z
    ((float*)&dpk[2 * d + 1])[0] = ad2;  // dst record word 4
}

// ---------------- K6: CSR layer-2 gather, 2 lanes per dst row + epilogue.
__global__ __launch_bounds__(256) void k_l2_gather(
    const int2* __restrict__ rowrange, const int* __restrict__ sorted,
    const float4* __restrict__ pk2f, const float* __restrict__ b2,
    float4* __restrict__ dpk, float* __restrict__ out, int n)
{
    int t = blockIdx.x * blockDim.x + threadIdx.x;
    int d = t >> 1, half = t & 1;
    if (d >= n) return;
    int2 rr = rowrange[d];
    int beg = rr.x, end = rr.y;
    float ad2 = pk2f[d].w;
    float se = 0.f, a0 = 0.f, a1 = 0.f;
    int i = beg + half;
    for (; i + 2 < end; i += 4) {
        int s0 = sorted[i], s1 = sorted[i + 2];
        float4 p0 = pk2f[s0], p1 = pk2f[s1];
        float e0 = __expf(lrelu(p0.x + ad2));
        float e1 = __expf(lrelu(p1.x + ad2));
        se += e0 + e1;
        a0 += e0 * p0.y + e1 * p1.y;
        a1 += e0 * p0.z + e1 * p1.z;
    }
    for (; i < end; i += 2) {
        float4 p = pk2f[sorted[i]];
        float ee = __expf(lrelu(p.x + ad2));
        se += ee; a0 += ee * p.y; a1 += ee * p.z;
    }
    se += __shfl_xor(se, 1);
    a0 += __shfl_xor(a0, 1);
    a1 += __shfl_xor(a1, 1);
    if (half) return;
    float rs2 = 1.0f / (se + 1e-16f);
    ((float*)&dpk[2 * d + 1])[1] = rs2;  // dst record word 5
    ((float2*)out)[d] = make_float2(a0 * rs2 + b2[0], a1 * rs2 + b2[1]);
}

// ---------------- K7: merged COO alpha pass, 2 ADJACENT edges/thread.
// Mem-instr budget per edge (the limiter — kernel is neither BW- nor
// VALU-bound): ei via one i2v pair-load per stream (1/edge), spack gather
// (1/edge), dst record float4+float2 from ONE 64B line (2 instr, 1 line),
// alpha2 one float2 per pair (0.5/edge), alpha1 staged in LDS then drained
// as lane-contiguous full-line NT stores (1/edge, no write amplification).
// E and Et are both even -> a pair never straddles the COO/self-loop
// boundary and never splits at Et.
__global__ __launch_bounds__(256) void k_alpha(
    const int* __restrict__ ei, const float4* __restrict__ spack,
    const float4* __restrict__ dpk,
    float4* __restrict__ alpha1, float2* __restrict__ alpha2_2, int E, int Et)
{
    __shared__ float4 lds[512];
    int t = threadIdx.x;
    int base = blockIdx.x * 512;
    int e0 = base + 2 * t;
    if (e0 < Et) {
        int s0, d0, s1, d1;
        if (e0 < E) {
            i2v ss = __builtin_nontemporal_load((const i2v*)(ei + e0));
            i2v dd = __builtin_nontemporal_load((const i2v*)(ei + E + e0));
            s0 = ss.x; s1 = ss.y; d0 = dd.x; d1 = dd.y;
        } else {
            s0 = e0 - E; d0 = s0; s1 = s0 + 1; d1 = s1;
        }
        float4 sp0 = spack[s0], sp1 = spack[s1];
        float4 dA0 = dpk[2 * d0], dA1 = dpk[2 * d1];
        float2 dB0 = *(const float2*)&dpk[2 * d0 + 1];
        float2 dB1 = *(const float2*)&dpk[2 * d1 + 1];

        float2 a01, a23, b01, b23, r01, r23;
        float4 al;
        // edge 0
        a01 = unpack2h(sp0.x); a23 = unpack2h(sp0.y);
        b01 = unpack2h(dA0.x); b23 = unpack2h(dA0.y);
        r01 = unpack2h(dA0.z); r23 = unpack2h(dA0.w);
        al.x = __expf(lrelu(a01.x + b01.x)) * r01.x;
        al.y = __expf(lrelu(a01.y + b01.y)) * r01.y;
        al.z = __expf(lrelu(a23.x + b23.x)) * r23.x;
        al.w = __expf(lrelu(a23.y + b23.y)) * r23.y;
        lds[t] = al;
        float o20 = __expf(lrelu(sp0.z + dB0.x)) * dB0.y;
        // edge 1
        a01 = unpack2h(sp1.x); a23 = unpack2h(sp1.y);
        b01 = unpack2h(dA1.x); b23 = unpack2h(dA1.y);
        r01 = unpack2h(dA1.z); r23 = unpack2h(dA1.w);
        al.x = __expf(lrelu(a01.x + b01.x)) * r01.x;
        al.y = __expf(lrelu(a01.y + b01.y)) * r01.y;
        al.z = __expf(lrelu(a23.x + b23.x)) * r23.x;
        al.w = __expf(lrelu(a23.y + b23.y)) * r23.y;
        lds[256 + t] = al;
        float o21 = __expf(lrelu(sp1.z + dB1.x)) * dB1.y;
        nt_store2(make_float2(o20, o21), &alpha2_2[(base >> 1) + t]);
    }
    __syncthreads();
    // drain: edge v of this block lives at lds[(v&1)*256 + (v>>1)]
    int v0 = t;
    if (base + v0 < Et)
        nt_store4(lds[(v0 & 1) * 256 + (v0 >> 1)], &alpha1[base + v0]);
    int v1 = t + 256;
    if (base + v1 < Et)
        nt_store4(lds[(v1 & 1) * 256 + 128 + (v1 >> 1) - 128], &alpha1[base + v1]);
}

extern "C" void kernel_launch(void* const* d_in, const int* in_sizes, int n_in,
                              void* d_out, int out_size, void* d_ws, size_t ws_size,
                              hipStream_t stream)
{
    const float* x   = (const float*)d_in[0];
    const int*   ei  = (const int*)d_in[1];
    const float* W1  = (const float*)d_in[3];
    const float* as1 = (const float*)d_in[4];
    const float* ad1 = (const float*)d_in[5];
    const float* b1  = (const float*)d_in[6];
    const float* W2  = (const float*)d_in[7];
    const float* as2 = (const float*)d_in[8];
    const float* ad2 = (const float*)d_in[9];
    const float* b2  = (const float*)d_in[10];

    const int n  = in_sizes[0] / 2;   // 100000
    const int E  = in_sizes[1] / 2;   // 3200000 (even)
    const int Et = E + n;             // even
    const int nb = (n + BW - 1) >> BSH;  // 196

    char* w = (char*)d_ws;
    float4* ga    = (float4*)w;  w += (size_t)n * sizeof(float4);
    float4* spack = (float4*)w;  w += (size_t)n * sizeof(float4);
    float4* dpk   = (float4*)w;  w += (size_t)n * 2 * sizeof(float4);  // 32B/node
    float4* pk2f  = (float4*)w;  w += (size_t)n * sizeof(float4);
    int2*   rowrange = (int2*)w; w += (size_t)n * sizeof(int2);
    int*    sorted   = (int*)w;  w += (size_t)nb * CAP * sizeof(int);
    int*    bucketCursor = (int*)w; w += (size_t)nb * sizeof(int);

    float*  out    = (float*)d_out;
    float4* alpha1 = (float4*)(out + (size_t)n * 2);
    float2* alpha2_2 = (float2*)(alpha1 + (size_t)Et);
    // binned scratch lives in the alpha1 output region, overwritten by k_alpha.
    unsigned int* binned = (unsigned int*)alpha1;

    dim3 blk(256);
    int gn   = (n + 255) / 256;
    int gn2  = (2 * n + 255) / 256;
    int gA   = (Et + 4095) / 4096;
    int gAl  = (Et + 511) / 512;

    k_l1_node  <<<gn,  blk, 0, stream>>>(x, W1, as1, ad1, ga, spack,
                                         dpk, bucketCursor, nb, n);
    k_binA     <<<gA,  blk, 0, stream>>>(ei, bucketCursor, binned, E, Et, nb);
    k_binB     <<<nb, dim3(1024), 0, stream>>>(binned, bucketCursor, sorted, rowrange, n, nb);
    k_l1_gather<<<gn2, blk, 0, stream>>>(rowrange, sorted, ga, dpk,
                                         W1, b1, W2, as2, ad2, pk2f, spack, n);
    k_l2_gather<<<gn2, blk, 0, stream>>>(rowrange, sorted, pk2f, b2,
                                         dpk, out, n);
    k_alpha    <<<gAl, blk, 0, stream>>>(ei, spack, dpk,
                                         alpha1, alpha2_2, E, Et);
}

// Round 3
// 284.323 us; speedup vs baseline: 1.0304x; 1.0189x over previous
//
#include <hip/hip_runtime.h>
#include <hip/hip_fp16.h>
#include <math.h>

#define NEG_SLOPE 0.2f
#define BW 512          // bucket node width
#define BSH 9           // log2(BW)
#define CAP 18432       // per-bucket edge capacity (mean ~16.9K)
#define NB_MAX 256

typedef float f4v __attribute__((ext_vector_type(4)));
typedef float f2v __attribute__((ext_vector_type(2)));
typedef int   i2v __attribute__((ext_vector_type(2)));

__device__ __forceinline__ float lrelu(float v) {
    return v > 0.0f ? v : NEG_SLOPE * v;
}
__device__ __forceinline__ float pack2h(float a, float b) {
    __half2 h = __floats2half2_rn(a, b);
    return *reinterpret_cast<float*>(&h);
}
__device__ __forceinline__ float2 unpack2h(float f) {
    __half2 h = *reinterpret_cast<__half2*>(&f);
    return __half22float2(h);
}
__device__ __forceinline__ void nt_store4(float4 v, float4* p) {
    f4v x = {v.x, v.y, v.z, v.w};
    __builtin_nontemporal_store(x, (f4v*)p);
}
__device__ __forceinline__ void nt_store2(float2 v, float2* p) {
    f2v x = {v.x, v.y};
    __builtin_nontemporal_store(x, (f2v*)p);
}

// ---------------- K1: node projection (+ zero bucket cursors).
// Compact tables (keep k_alpha's gather set = spack 1.6MB + dpack 1.6MB +
// dpk2hf 0.4MB = 3.6MB < 4MB per-XCD L2; the 32B-record experiment pushed
// this to 4.8MB -> +52MB HBM fetch in k_alpha).
// ga[i]={as01h,as23h,x0,x1}; spack[i]={as01h,as23h, as2(later), 0};
// dpack[i]={ad01h,ad23h, rs01h,rs23h(later)}; dpk2hf[i]={ad2h,rs2h}(later).
__global__ __launch_bounds__(256) void k_l1_node(
    const float* __restrict__ x, const float* __restrict__ W1,
    const float* __restrict__ asw, const float* __restrict__ adw,
    float4* __restrict__ ga, float4* __restrict__ spack,
    float2* __restrict__ dpack2, int* __restrict__ bucketCursor,
    int nb, int n)
{
    int i = blockIdx.x * blockDim.x + threadIdx.x;
    if (i < nb) bucketCursor[i] = 0;
    if (i >= n) return;
    float2 xv = ((const float2*)x)[i];
    float as[4] = {0.f, 0.f, 0.f, 0.f};
    float ad[4] = {0.f, 0.f, 0.f, 0.f};
    #pragma unroll
    for (int j = 0; j < 32; ++j) {
        float h = xv.x * W1[j] + xv.y * W1[32 + j];
        as[j >> 3] += h * asw[j];
        ad[j >> 3] += h * adw[j];
    }
    float p01 = pack2h(as[0], as[1]), p23 = pack2h(as[2], as[3]);
    ga[i] = make_float4(p01, p23, xv.x, xv.y);
    spack[i] = make_float4(p01, p23, 0.f, 0.f);
    dpack2[2 * i] = make_float2(pack2h(ad[0], ad[1]), pack2h(ad[2], ad[3]));
}

// ---------------- KA: LDS-binned bucket scatter (4096 edges/block).
__global__ __launch_bounds__(256) void k_binA(
    const int* __restrict__ ei, int* __restrict__ bucketCursor,
    unsigned int* __restrict__ binned, int E, int Et, int nb)
{
    __shared__ int cnt[NB_MAX], lscan[NB_MAX], base[NB_MAX], lcur[NB_MAX];
    __shared__ unsigned int staging[4096];
    __shared__ short sbk[4096];
    int t = threadIdx.x;
    int c0 = blockIdx.x * 4096;
    unsigned int ent[16];
    short bb[16];
    #pragma unroll
    for (int k = 0; k < 16; ++k) {
        int e = c0 + k * 256 + t;
        int s, d;
        if (e < E) {
            s = __builtin_nontemporal_load(&ei[e]);
            d = __builtin_nontemporal_load(&ei[E + e]);
        } else { s = e - E; d = s; }
        bool valid = e < Et;
        bb[k] = valid ? (short)(d >> BSH) : (short)(-1);
        ent[k] = ((unsigned int)s << BSH) | (unsigned int)(d & (BW - 1));
    }
    cnt[t] = 0;
    __syncthreads();
    #pragma unroll
    for (int k = 0; k < 16; ++k)
        if (bb[k] >= 0) atomicAdd(&cnt[bb[k]], 1);
    __syncthreads();
    int c = cnt[t];
    lscan[t] = c;
    __syncthreads();
    // parallel inclusive scan over 256 entries
    for (int off = 1; off < 256; off <<= 1) {
        int v = (t >= off) ? lscan[t - off] : 0;
        __syncthreads();
        lscan[t] += v;
        __syncthreads();
    }
    int tot = lscan[255];
    int ex = lscan[t] - c;
    __syncthreads();
    lscan[t] = ex;          // chunk-local exclusive start of bucket t
    lcur[t] = ex;
    if (t < nb && c > 0) base[t] = atomicAdd(&bucketCursor[t], c);
    __syncthreads();
    #pragma unroll
    for (int k = 0; k < 16; ++k)
        if (bb[k] >= 0) {
            int p = atomicAdd(&lcur[bb[k]], 1);
            staging[p] = ent[k];
            sbk[p] = bb[k];
        }
    __syncthreads();
    for (int j = t; j < tot; j += 256) {
        int lo = sbk[j];
        __builtin_nontemporal_store(staging[j],
            &binned[(size_t)lo * CAP + base[lo] + (j - lscan[lo])]);
    }
}

// ---------------- KB: per-bucket counting sort -> CSR (1024 threads).
__global__ __launch_bounds__(1024) void k_binB(
    const unsigned int* __restrict__ binned, const int* __restrict__ bucketCursor,
    int* __restrict__ sorted, int2* __restrict__ rowrange, int n, int nb)
{
    __shared__ int cnt[BW], cur[BW];
    int t = threadIdx.x;
    int b = blockIdx.x;
    int m = bucketCursor[b];
    size_t base = (size_t)b * CAP;
    int node0 = b << BSH;
    if (t < BW) cnt[t] = 0;
    __syncthreads();
    for (int i = t; i < m; i += 1024)
        atomicAdd(&cnt[binned[base + i] & (BW - 1)], 1);
    __syncthreads();
    int deg = (t < BW) ? cnt[t] : 0;
    for (int off = 1; off < BW; off <<= 1) {
        int v = (t >= off && t < BW) ? cnt[t - off] : 0;
        __syncthreads();
        if (t < BW) cnt[t] += v;
        __syncthreads();
    }
    if (t < BW) {
        int ex = cnt[t] - deg;
        cur[t] = ex;
        int node = node0 + t;
        if (node < n)
            rowrange[node] = make_int2((int)base + ex, (int)base + ex + deg);
    }
    __syncthreads();
    for (int i = t; i < m; i += 1024) {
        unsigned int en = binned[base + i];
        int dl = (int)(en & (BW - 1));
        int p = atomicAdd(&cur[dl], 1);
        sorted[base + p] = (int)(en >> BSH);
    }
}

// ---------------- K5: CSR layer-1 gather, 8 lanes per dst row + L2 prep.
// 8 lanes/row: 800K threads -> 3125 blocks -> waves/CU at the 32 cap
// (was 2 lanes/row: 781 blocks, ~12 waves/CU, latency-starved) and the
// dependent sorted->ga chain drops ~17 -> ~4 iterations per lane.
__global__ __launch_bounds__(256) void k_l1_gather(
    const int2* __restrict__ rowrange, const int* __restrict__ sorted,
    const float4* __restrict__ ga, float2* __restrict__ dpack2,
    const float* __restrict__ W1, const float* __restrict__ b1,
    const float* __restrict__ W2,
    const float* __restrict__ asw2, const float* __restrict__ adw2,
    float4* __restrict__ pk2f, float4* __restrict__ spack,
    __half* __restrict__ dpk2h, int n)
{
    int t = blockIdx.x * blockDim.x + threadIdx.x;
    int d = t >> 3, q = t & 7;
    if (d >= n) return;
    int2 rr = rowrange[d];
    int beg = rr.x, end = rr.y;
    float2 adp = dpack2[2 * d];
    float2 ad01 = unpack2h(adp.x), ad23 = unpack2h(adp.y);
    float see[4] = {0.f, 0.f, 0.f, 0.f};
    float sx0[4] = {0.f, 0.f, 0.f, 0.f};
    float sx1[4] = {0.f, 0.f, 0.f, 0.f};
    int i = beg + q;
    for (; i + 8 < end; i += 16) {
        int s0 = sorted[i], s1 = sorted[i + 8];
        float4 v0 = ga[s0], v1 = ga[s1];
        #pragma unroll
        for (int k = 0; k < 2; ++k) {
            float4 v = k ? v1 : v0;
            float2 a01 = unpack2h(v.x), a23 = unpack2h(v.y);
            float e0 = __expf(lrelu(a01.x + ad01.x));
            float e1 = __expf(lrelu(a01.y + ad01.y));
            float e2 = __expf(lrelu(a23.x + ad23.x));
            float e3 = __expf(lrelu(a23.y + ad23.y));
            see[0] += e0; sx0[0] += e0 * v.z; sx1[0] += e0 * v.w;
            see[1] += e1; sx0[1] += e1 * v.z; sx1[1] += e1 * v.w;
            see[2] += e2; sx0[2] += e2 * v.z; sx1[2] += e2 * v.w;
            see[3] += e3; sx0[3] += e3 * v.z; sx1[3] += e3 * v.w;
        }
    }
    for (; i < end; i += 8) {
        float4 v = ga[sorted[i]];
        float2 a01 = unpack2h(v.x), a23 = unpack2h(v.y);
        float e0 = __expf(lrelu(a01.x + ad01.x));
        float e1 = __expf(lrelu(a01.y + ad01.y));
        float e2 = __expf(lrelu(a23.x + ad23.x));
        float e3 = __expf(lrelu(a23.y + ad23.y));
        see[0] += e0; sx0[0] += e0 * v.z; sx1[0] += e0 * v.w;
        see[1] += e1; sx0[1] += e1 * v.z; sx1[1] += e1 * v.w;
        see[2] += e2; sx0[2] += e2 * v.z; sx1[2] += e2 * v.w;
        see[3] += e3; sx0[3] += e3 * v.z; sx1[3] += e3 * v.w;
    }
    // reduce across the 8-lane group
    #pragma unroll
    for (int h = 0; h < 4; ++h) {
        see[h] += __shfl_xor(see[h], 1);
        sx0[h] += __shfl_xor(sx0[h], 1);
        sx1[h] += __shfl_xor(sx1[h], 1);
        see[h] += __shfl_xor(see[h], 2);
        sx0[h] += __shfl_xor(sx0[h], 2);
        sx1[h] += __shfl_xor(sx1[h], 2);
        see[h] += __shfl_xor(see[h], 4);
        sx0[h] += __shfl_xor(sx0[h], 4);
        sx1[h] += __shfl_xor(sx1[h], 4);
    }
    if (q) return;
    float rs[4];
    #pragma unroll
    for (int h = 0; h < 4; ++h) rs[h] = 1.0f / (see[h] + 1e-16f);
    dpack2[2 * d + 1] = make_float2(pack2h(rs[0], rs[1]), pack2h(rs[2], rs[3]));
    float h20 = 0.f, h21 = 0.f;
    #pragma unroll
    for (int j = 0; j < 32; ++j) {
        int h = j >> 3;
        float num = W1[j] * sx0[h] + W1[32 + j] * sx1[h];
        float o = num * rs[h] + b1[j];
        float he = o > 0.f ? o : expm1f(o);
        h20 += he * W2[2 * j];
        h21 += he * W2[2 * j + 1];
    }
    float as2 = h20 * asw2[0] + h21 * asw2[1];
    float ad2 = h20 * adw2[0] + h21 * adw2[1];
    pk2f[d] = make_float4(as2, h20, h21, ad2);
    ((float*)&spack[d])[2] = as2;        // spack.z
    dpk2h[2 * d] = __float2half(ad2);    // low half of packed {ad2h, rs2h}
}

// ---------------- K6: CSR layer-2 gather, 8 lanes per dst row + epilogue.
__global__ __launch_bounds__(256) void k_l2_gather(
    const int2* __restrict__ rowrange, const int* __restrict__ sorted,
    const float4* __restrict__ pk2f, const float* __restrict__ b2,
    __half* __restrict__ dpk2h, float* __restrict__ out, int n)
{
    int t = blockIdx.x * blockDim.x + threadIdx.x;
    int d = t >> 3, q = t & 7;
    if (d >= n) return;
    int2 rr = rowrange[d];
    int beg = rr.x, end = rr.y;
    float ad2 = pk2f[d].w;
    float se = 0.f, a0 = 0.f, a1 = 0.f;
    int i = beg + q;
    for (; i + 8 < end; i += 16) {
        int s0 = sorted[i], s1 = sorted[i + 8];
        float4 p0 = pk2f[s0], p1 = pk2f[s1];
        float e0 = __expf(lrelu(p0.x + ad2));
        float e1 = __expf(lrelu(p1.x + ad2));
        se += e0 + e1;
        a0 += e0 * p0.y + e1 * p1.y;
        a1 += e0 * p0.z + e1 * p1.z;
    }
    for (; i < end; i += 8) {
        float4 p = pk2f[sorted[i]];
        float ee = __expf(lrelu(p.x + ad2));
        se += ee; a0 += ee * p.y; a1 += ee * p.z;
    }
    se += __shfl_xor(se, 1); a0 += __shfl_xor(a0, 1); a1 += __shfl_xor(a1, 1);
    se += __shfl_xor(se, 2); a0 += __shfl_xor(a0, 2); a1 += __shfl_xor(a1, 2);
    se += __shfl_xor(se, 4); a0 += __shfl_xor(a0, 4); a1 += __shfl_xor(a1, 4);
    if (q) return;
    float rs2 = 1.0f / (se + 1e-16f);
    dpk2h[2 * d + 1] = __float2half(rs2);  // high half of {ad2h, rs2h}
    ((float2*)out)[d] = make_float2(a0 * rs2 + b2[0], a1 * rs2 + b2[1]);
}

// ---------------- K7: merged COO alpha pass, 2 ADJACENT edges/thread.
// Paired i2v ei loads + compact-table gathers (spack 16B, dpack 16B,
// dpk2hf 4B — all L2-resident); alpha1 staged in LDS then drained as
// lane-contiguous full-line NT stores; alpha2 one float2 per pair.
__global__ __launch_bounds__(256) void k_alpha(
    const int* __restrict__ ei, const float4* __restrict__ spack,
    const float4* __restrict__ dpack, const float* __restrict__ dpk2hf,
    float4* __restrict__ alpha1, float2* __restrict__ alpha2_2, int E, int Et)
{
    __shared__ float4 lds[512];
    int t = threadIdx.x;
    int base = blockIdx.x * 512;
    int e0 = base + 2 * t;
    if (e0 < Et) {
        int s0, d0, s1, d1;
        if (e0 < E) {
            i2v ss = __builtin_nontemporal_load((const i2v*)(ei + e0));
            i2v dd = __builtin_nontemporal_load((const i2v*)(ei + E + e0));
            s0 = ss.x; s1 = ss.y; d0 = dd.x; d1 = dd.y;
        } else {
            s0 = e0 - E; d0 = s0; s1 = s0 + 1; d1 = s1;
        }
        float4 sp0 = spack[s0], sp1 = spack[s1];
        float4 dp0 = dpack[d0], dp1 = dpack[d1];
        float  dh0 = dpk2hf[d0], dh1 = dpk2hf[d1];

        float2 a01, a23, b01, b23, r01, r23, ar;
        float4 al;
        // edge 0
        a01 = unpack2h(sp0.x); a23 = unpack2h(sp0.y);
        b01 = unpack2h(dp0.x); b23 = unpack2h(dp0.y);
        r01 = unpack2h(dp0.z); r23 = unpack2h(dp0.w);
        al.x = __expf(lrelu(a01.x + b01.x)) * r01.x;
        al.y = __expf(lrelu(a01.y + b01.y)) * r01.y;
        al.z = __expf(lrelu(a23.x + b23.x)) * r23.x;
        al.w = __expf(lrelu(a23.y + b23.y)) * r23.y;
        lds[t] = al;
        ar = unpack2h(dh0);
        float o20 = __expf(lrelu(sp0.z + ar.x)) * ar.y;
        // edge 1
        a01 = unpack2h(sp1.x); a23 = unpack2h(sp1.y);
        b01 = unpack2h(dp1.x); b23 = unpack2h(dp1.y);
        r01 = unpack2h(dp1.z); r23 = unpack2h(dp1.w);
        al.x = __expf(lrelu(a01.x + b01.x)) * r01.x;
        al.y = __expf(lrelu(a01.y + b01.y)) * r01.y;
        al.z = __expf(lrelu(a23.x + b23.x)) * r23.x;
        al.w = __expf(lrelu(a23.y + b23.y)) * r23.y;
        lds[256 + t] = al;
        ar = unpack2h(dh1);
        float o21 = __expf(lrelu(sp1.z + ar.x)) * ar.y;
        nt_store2(make_float2(o20, o21), &alpha2_2[(base >> 1) + t]);
    }
    __syncthreads();
    // drain: edge v of this block lives at lds[(v&1)*256 + (v>>1)]
    int v0 = t;
    if (base + v0 < Et)
        nt_store4(lds[(v0 & 1) * 256 + (v0 >> 1)], &alpha1[base + v0]);
    int v1 = t + 256;
    if (base + v1 < Et)
        nt_store4(lds[(v1 & 1) * 256 + (v1 >> 1)], &alpha1[base + v1]);
}

extern "C" void kernel_launch(void* const* d_in, const int* in_sizes, int n_in,
                              void* d_out, int out_size, void* d_ws, size_t ws_size,
                              hipStream_t stream)
{
    const float* x   = (const float*)d_in[0];
    const int*   ei  = (const int*)d_in[1];
    const float* W1  = (const float*)d_in[3];
    const float* as1 = (const float*)d_in[4];
    const float* ad1 = (const float*)d_in[5];
    const float* b1  = (const float*)d_in[6];
    const float* W2  = (const float*)d_in[7];
    const float* as2 = (const float*)d_in[8];
    const float* ad2 = (const float*)d_in[9];
    const float* b2  = (const float*)d_in[10];

    const int n  = in_sizes[0] / 2;   // 100000
    const int E  = in_sizes[1] / 2;   // 3200000 (even)
    const int Et = E + n;             // even
    const int nb = (n + BW - 1) >> BSH;  // 196

    char* w = (char*)d_ws;
    float4* ga    = (float4*)w;  w += (size_t)n * sizeof(float4);
    float4* spack = (float4*)w;  w += (size_t)n * sizeof(float4);
    float4* dpack = (float4*)w;  w += (size_t)n * sizeof(float4);
    float4* pk2f  = (float4*)w;  w += (size_t)n * sizeof(float4);
    float*  dpk2hf= (float*)w;   w += (size_t)n * sizeof(float);
    int2*   rowrange = (int2*)w; w += (size_t)n * sizeof(int2);
    int*    sorted   = (int*)w;  w += (size_t)nb * CAP * sizeof(int);
    int*    bucketCursor = (int*)w; w += (size_t)nb * sizeof(int);

    float*  out    = (float*)d_out;
    float4* alpha1 = (float4*)(out + (size_t)n * 2);
    float2* alpha2_2 = (float2*)(alpha1 + (size_t)Et);
    // binned scratch lives in the alpha1 output region, overwritten by k_alpha.
    unsigned int* binned = (unsigned int*)alpha1;

    dim3 blk(256);
    int gn   = (n + 255) / 256;
    int gn8  = (8 * n + 255) / 256;
    int gA   = (Et + 4095) / 4096;
    int gAl  = (Et + 511) / 512;

    k_l1_node  <<<gn,  blk, 0, stream>>>(x, W1, as1, ad1, ga, spack,
                                         (float2*)dpack, bucketCursor, nb, n);
    k_binA     <<<gA,  blk, 0, stream>>>(ei, bucketCursor, binned, E, Et, nb);
    k_binB     <<<nb, dim3(1024), 0, stream>>>(binned, bucketCursor, sorted, rowrange, n, nb);
    k_l1_gather<<<gn8, blk, 0, stream>>>(rowrange, sorted, ga, (float2*)dpack,
                                         W1, b1, W2, as2, ad2, pk2f, spack,
                                         (__half*)dpk2hf, n);
    k_l2_gather<<<gn8, blk, 0, stream>>>(rowrange, sorted, pk2f, b2,
                                         (__half*)dpk2hf, out, n);
    k_alpha    <<<gAl, blk, 0, stream>>>(ei, spack, dpack, dpk2hf,
                                         alpha1, alpha2_2, E, Et);
}

// Round 4
// 275.692 us; speedup vs baseline: 1.0626x; 1.0313x over previous
//
#include <hip/hip_runtime.h>
#include <hip/hip_fp16.h>
#include <math.h>

#define NEG_SLOPE 0.2f
#define BW 512          // bucket node width
#define BSH 9           // log2(BW)
#define CAP 18432       // per-bucket edge capacity (mean ~16.9K)
#define NB_MAX 256

typedef float f4v __attribute__((ext_vector_type(4)));
typedef float f2v __attribute__((ext_vector_type(2)));
typedef int   i2v __attribute__((ext_vector_type(2)));

__device__ __forceinline__ float lrelu(float v) {
    return v > 0.0f ? v : NEG_SLOPE * v;
}
__device__ __forceinline__ float pack2h(float a, float b) {
    __half2 h = __floats2half2_rn(a, b);
    return *reinterpret_cast<float*>(&h);
}
__device__ __forceinline__ float2 unpack2h(float f) {
    __half2 h = *reinterpret_cast<__half2*>(&f);
    return __half22float2(h);
}
__device__ __forceinline__ void nt_store4(float4 v, float4* p) {
    f4v x = {v.x, v.y, v.z, v.w};
    __builtin_nontemporal_store(x, (f4v*)p);
}
__device__ __forceinline__ void nt_store2(float2 v, float2* p) {
    f2v x = {v.x, v.y};
    __builtin_nontemporal_store(x, (f2v*)p);
}

// Unified 32B node record npk[i] (two float4, 64B-line-aligned pairs):
//   lo = npk[2i]   = { as01h, as23h, as2, ad2rs2h }
//   hi = npk[2i+1] = { ad01h, ad23h, rs01h, rs23h }
// k_alpha src side: one dwordx4 (lo) -> 1 line touch.
// k_alpha dst side: hi dwordx4 + lo.w dword -> SAME 64B line -> 1 line touch.
// Table = 3.2MB < 4MB/XCD L2 (R2's 4.8MB split-table variant spilled: +52MB fetch).

// ---------------- K1: node projection (+ zero bucket cursors).
__global__ __launch_bounds__(256) void k_l1_node(
    const float* __restrict__ x, const float* __restrict__ W1,
    const float* __restrict__ asw, const float* __restrict__ adw,
    float4* __restrict__ ga, float4* __restrict__ npk,
    int* __restrict__ bucketCursor, int nb, int n)
{
    int i = blockIdx.x * blockDim.x + threadIdx.x;
    if (i < nb) bucketCursor[i] = 0;
    if (i >= n) return;
    float2 xv = ((const float2*)x)[i];
    float as[4] = {0.f, 0.f, 0.f, 0.f};
    float ad[4] = {0.f, 0.f, 0.f, 0.f};
    #pragma unroll
    for (int j = 0; j < 32; ++j) {
        float h = xv.x * W1[j] + xv.y * W1[32 + j];
        as[j >> 3] += h * asw[j];
        ad[j >> 3] += h * adw[j];
    }
    float p01 = pack2h(as[0], as[1]), p23 = pack2h(as[2], as[3]);
    ga[i] = make_float4(p01, p23, xv.x, xv.y);
    npk[2 * i]     = make_float4(p01, p23, 0.f, 0.f);
    npk[2 * i + 1] = make_float4(pack2h(ad[0], ad[1]), pack2h(ad[2], ad[3]), 0.f, 0.f);
}

// ---------------- KA: LDS-binned bucket scatter (4096 edges/block).
// ei loads vectorized: paired i2v (E even -> a pair never straddles the
// COO/self-loop boundary). Slot->edge mapping changed vs scalar version,
// but binning is order-agnostic.
__global__ __launch_bounds__(256) void k_binA(
    const int* __restrict__ ei, int* __restrict__ bucketCursor,
    unsigned int* __restrict__ binned, int E, int Et, int nb)
{
    __shared__ int cnt[NB_MAX], lscan[NB_MAX], base[NB_MAX], lcur[NB_MAX];
    __shared__ unsigned int staging[4096];
    __shared__ short sbk[4096];
    int t = threadIdx.x;
    int c0 = blockIdx.x * 4096;
    unsigned int ent[16];
    short bb[16];
    #pragma unroll
    for (int k = 0; k < 8; ++k) {
        int e0 = c0 + 2 * (k * 256 + t);
        int s0, d0, s1, d1;
        if (e0 < E) {
            i2v ss = __builtin_nontemporal_load((const i2v*)(ei + e0));
            i2v dd = __builtin_nontemporal_load((const i2v*)(ei + E + e0));
            s0 = ss.x; s1 = ss.y; d0 = dd.x; d1 = dd.y;
        } else { s0 = e0 - E; d0 = s0; s1 = s0 + 1; d1 = s1; }
        bool valid = e0 < Et;   // e0 even, Et even -> e0,e1 valid together
        bb[2 * k]     = valid ? (short)(d0 >> BSH) : (short)(-1);
        bb[2 * k + 1] = valid ? (short)(d1 >> BSH) : (short)(-1);
        ent[2 * k]     = ((unsigned int)s0 << BSH) | (unsigned int)(d0 & (BW - 1));
        ent[2 * k + 1] = ((unsigned int)s1 << BSH) | (unsigned int)(d1 & (BW - 1));
    }
    cnt[t] = 0;
    __syncthreads();
    #pragma unroll
    for (int k = 0; k < 16; ++k)
        if (bb[k] >= 0) atomicAdd(&cnt[bb[k]], 1);
    __syncthreads();
    int c = cnt[t];
    lscan[t] = c;
    __syncthreads();
    // parallel inclusive scan over 256 entries
    for (int off = 1; off < 256; off <<= 1) {
        int v = (t >= off) ? lscan[t - off] : 0;
        __syncthreads();
        lscan[t] += v;
        __syncthreads();
    }
    int tot = lscan[255];
    int ex = lscan[t] - c;
    __syncthreads();
    lscan[t] = ex;          // chunk-local exclusive start of bucket t
    lcur[t] = ex;
    if (t < nb && c > 0) base[t] = atomicAdd(&bucketCursor[t], c);
    __syncthreads();
    #pragma unroll
    for (int k = 0; k < 16; ++k)
        if (bb[k] >= 0) {
            int p = atomicAdd(&lcur[bb[k]], 1);
            staging[p] = ent[k];
            sbk[p] = bb[k];
        }
    __syncthreads();
    for (int j = t; j < tot; j += 256) {
        int lo = sbk[j];
        __builtin_nontemporal_store(staging[j],
            &binned[(size_t)lo * CAP + base[lo] + (j - lscan[lo])]);
    }
}

// ---------------- KB: per-bucket counting sort -> CSR (1024 threads).
__global__ __launch_bounds__(1024) void k_binB(
    const unsigned int* __restrict__ binned, const int* __restrict__ bucketCursor,
    int* __restrict__ sorted, int2* __restrict__ rowrange, int n, int nb)
{
    __shared__ int cnt[BW], cur[BW];
    int t = threadIdx.x;
    int b = blockIdx.x;
    int m = bucketCursor[b];
    size_t base = (size_t)b * CAP;
    int node0 = b << BSH;
    if (t < BW) cnt[t] = 0;
    __syncthreads();
    for (int i = t; i < m; i += 1024)
        atomicAdd(&cnt[binned[base + i] & (BW - 1)], 1);
    __syncthreads();
    int deg = (t < BW) ? cnt[t] : 0;
    for (int off = 1; off < BW; off <<= 1) {
        int v = (t >= off && t < BW) ? cnt[t - off] : 0;
        __syncthreads();
        if (t < BW) cnt[t] += v;
        __syncthreads();
    }
    if (t < BW) {
        int ex = cnt[t] - deg;
        cur[t] = ex;
        int node = node0 + t;
        if (node < n)
            rowrange[node] = make_int2((int)base + ex, (int)base + ex + deg);
    }
    __syncthreads();
    for (int i = t; i < m; i += 1024) {
        unsigned int en = binned[base + i];
        int dl = (int)(en & (BW - 1));
        int p = atomicAdd(&cur[dl], 1);
        sorted[base + p] = (int)(en >> BSH);
    }
}

// ---------------- K5: CSR layer-1 gather, 8 lanes per dst row + L2 prep.
__global__ __launch_bounds__(256) void k_l1_gather(
    const int2* __restrict__ rowrange, const int* __restrict__ sorted,
    const float4* __restrict__ ga, float4* __restrict__ npk,
    const float* __restrict__ W1, const float* __restrict__ b1,
    const float* __restrict__ W2,
    const float* __restrict__ asw2, const float* __restrict__ adw2,
    float4* __restrict__ pk2f, int n)
{
    int t = blockIdx.x * blockDim.x + threadIdx.x;
    int d = t >> 3, q = t & 7;
    if (d >= n) return;
    int2 rr = rowrange[d];
    int beg = rr.x, end = rr.y;
    float2 adp = *(const float2*)&npk[2 * d + 1];   // {ad01h, ad23h}
    float2 ad01 = unpack2h(adp.x), ad23 = unpack2h(adp.y);
    float see[4] = {0.f, 0.f, 0.f, 0.f};
    float sx0[4] = {0.f, 0.f, 0.f, 0.f};
    float sx1[4] = {0.f, 0.f, 0.f, 0.f};
    int i = beg + q;
    for (; i + 8 < end; i += 16) {
        int s0 = sorted[i], s1 = sorted[i + 8];
        float4 v0 = ga[s0], v1 = ga[s1];
        #pragma unroll
        for (int k = 0; k < 2; ++k) {
            float4 v = k ? v1 : v0;
            float2 a01 = unpack2h(v.x), a23 = unpack2h(v.y);
            float e0 = __expf(lrelu(a01.x + ad01.x));
            float e1 = __expf(lrelu(a01.y + ad01.y));
            float e2 = __expf(lrelu(a23.x + ad23.x));
            float e3 = __expf(lrelu(a23.y + ad23.y));
            see[0] += e0; sx0[0] += e0 * v.z; sx1[0] += e0 * v.w;
            see[1] += e1; sx0[1] += e1 * v.z; sx1[1] += e1 * v.w;
            see[2] += e2; sx0[2] += e2 * v.z; sx1[2] += e2 * v.w;
            see[3] += e3; sx0[3] += e3 * v.z; sx1[3] += e3 * v.w;
        }
    }
    for (; i < end; i += 8) {
        float4 v = ga[sorted[i]];
        float2 a01 = unpack2h(v.x), a23 = unpack2h(v.y);
        float e0 = __expf(lrelu(a01.x + ad01.x));
        float e1 = __expf(lrelu(a01.y + ad01.y));
        float e2 = __expf(lrelu(a23.x + ad23.x));
        float e3 = __expf(lrelu(a23.y + ad23.y));
        see[0] += e0; sx0[0] += e0 * v.z; sx1[0] += e0 * v.w;
        see[1] += e1; sx0[1] += e1 * v.z; sx1[1] += e1 * v.w;
        see[2] += e2; sx0[2] += e2 * v.z; sx1[2] += e2 * v.w;
        see[3] += e3; sx0[3] += e3 * v.z; sx1[3] += e3 * v.w;
    }
    // reduce across the 8-lane group
    #pragma unroll
    for (int h = 0; h < 4; ++h) {
        see[h] += __shfl_xor(see[h], 1);
        sx0[h] += __shfl_xor(sx0[h], 1);
        sx1[h] += __shfl_xor(sx1[h], 1);
        see[h] += __shfl_xor(see[h], 2);
        sx0[h] += __shfl_xor(sx0[h], 2);
        sx1[h] += __shfl_xor(sx1[h], 2);
        see[h] += __shfl_xor(see[h], 4);
        sx0[h] += __shfl_xor(sx0[h], 4);
        sx1[h] += __shfl_xor(sx1[h], 4);
    }
    if (q) return;
    float rs[4];
    #pragma unroll
    for (int h = 0; h < 4; ++h) rs[h] = 1.0f / (see[h] + 1e-16f);
    // hi words 2,3 = {rs01h, rs23h}
    ((float2*)&npk[2 * d + 1])[1] = make_float2(pack2h(rs[0], rs[1]), pack2h(rs[2], rs[3]));
    float h20 = 0.f, h21 = 0.f;
    #pragma unroll
    for (int j = 0; j < 32; ++j) {
        int h = j >> 3;
        float num = W1[j] * sx0[h] + W1[32 + j] * sx1[h];
        float o = num * rs[h] + b1[j];
        float he = o > 0.f ? o : expm1f(o);
        h20 += he * W2[2 * j];
        h21 += he * W2[2 * j + 1];
    }
    float as2 = h20 * asw2[0] + h21 * asw2[1];
    float ad2 = h20 * adw2[0] + h21 * adw2[1];
    pk2f[d] = make_float4(as2, h20, h21, ad2);
    ((float*)&npk[2 * d])[2] = as2;                      // lo.z
    ((__half*)&npk[2 * d])[6] = __float2half(ad2);       // lo.w low half
}

// ---------------- K6: CSR layer-2 gather, 8 lanes per dst row + epilogue.
__global__ __launch_bounds__(256) void k_l2_gather(
    const int2* __restrict__ rowrange, const int* __restrict__ sorted,
    const float4* __restrict__ pk2f, const float* __restrict__ b2,
    float4* __restrict__ npk, float* __restrict__ out, int n)
{
    int t = blockIdx.x * blockDim.x + threadIdx.x;
    int d = t >> 3, q = t & 7;
    if (d >= n) return;
    int2 rr = rowrange[d];
    int beg = rr.x, end = rr.y;
    float ad2 = pk2f[d].w;
    float se = 0.f, a0 = 0.f, a1 = 0.f;
    int i = beg + q;
    for (; i + 8 < end; i += 16) {
        int s0 = sorted[i], s1 = sorted[i + 8];
        float4 p0 = pk2f[s0], p1 = pk2f[s1];
        float e0 = __expf(lrelu(p0.x + ad2));
        float e1 = __expf(lrelu(p1.x + ad2));
        se += e0 + e1;
        a0 += e0 * p0.y + e1 * p1.y;
        a1 += e0 * p0.z + e1 * p1.z;
    }
    for (; i < end; i += 8) {
        float4 p = pk2f[sorted[i]];
        float ee = __expf(lrelu(p.x + ad2));
        se += ee; a0 += ee * p.y; a1 += ee * p.z;
    }
    se += __shfl_xor(se, 1); a0 += __shfl_xor(a0, 1); a1 += __shfl_xor(a1, 1);
    se += __shfl_xor(se, 2); a0 += __shfl_xor(a0, 2); a1 += __shfl_xor(a1, 2);
    se += __shfl_xor(se, 4); a0 += __shfl_xor(a0, 4); a1 += __shfl_xor(a1, 4);
    if (q) return;
    float rs2 = 1.0f / (se + 1e-16f);
    ((__half*)&npk[2 * d])[7] = __float2half(rs2);   // lo.w high half
    ((float2*)out)[d] = make_float2(a0 * rs2 + b2[0], a1 * rs2 + b2[1]);
}

// ---------------- K7: merged COO alpha pass, 2 ADJACENT edges/thread.
// 2 random line-touches per edge (was 3): src = npk lo dwordx4; dst =
// npk hi dwordx4 + lo.w dword, both within the SAME 64B line (32B-aligned
// records). Table 3.2MB L2-resident. alpha1 staged in LDS, drained as
// lane-contiguous full-line NT stores; alpha2 one float2 per pair.
__global__ __launch_bounds__(256) void k_alpha(
    const int* __restrict__ ei, const float4* __restrict__ npk,
    float4* __restrict__ alpha1, float2* __restrict__ alpha2_2, int E, int Et)
{
    __shared__ float4 lds[512];
    int t = threadIdx.x;
    int base = blockIdx.x * 512;
    int e0 = base + 2 * t;
    if (e0 < Et) {
        int s0, d0, s1, d1;
        if (e0 < E) {
            i2v ss = __builtin_nontemporal_load((const i2v*)(ei + e0));
            i2v dd = __builtin_nontemporal_load((const i2v*)(ei + E + e0));
            s0 = ss.x; s1 = ss.y; d0 = dd.x; d1 = dd.y;
        } else {
            s0 = e0 - E; d0 = s0; s1 = s0 + 1; d1 = s1;
        }
        float4 lo0 = npk[2 * s0], lo1 = npk[2 * s1];          // src: 1 line
        float4 hi0 = npk[2 * d0 + 1], hi1 = npk[2 * d1 + 1];  // dst: same line as
        float  w30 = ((const float*)npk)[8 * d0 + 3];         //      lo.w below
        float  w31 = ((const float*)npk)[8 * d1 + 3];

        float2 a01, a23, b01, b23, r01, r23, ar;
        float4 al;
        // edge 0
        a01 = unpack2h(lo0.x); a23 = unpack2h(lo0.y);
        b01 = unpack2h(hi0.x); b23 = unpack2h(hi0.y);
        r01 = unpack2h(hi0.z); r23 = unpack2h(hi0.w);
        al.x = __expf(lrelu(a01.x + b01.x)) * r01.x;
        al.y = __expf(lrelu(a01.y + b01.y)) * r01.y;
        al.z = __expf(lrelu(a23.x + b23.x)) * r23.x;
        al.w = __expf(lrelu(a23.y + b23.y)) * r23.y;
        lds[t] = al;
        ar = unpack2h(w30);
        float o20 = __expf(lrelu(lo0.z + ar.x)) * ar.y;
        // edge 1
        a01 = unpack2h(lo1.x); a23 = unpack2h(lo1.y);
        b01 = unpack2h(hi1.x); b23 = unpack2h(hi1.y);
        r01 = unpack2h(hi1.z); r23 = unpack2h(hi1.w);
        al.x = __expf(lrelu(a01.x + b01.x)) * r01.x;
        al.y = __expf(lrelu(a01.y + b01.y)) * r01.y;
        al.z = __expf(lrelu(a23.x + b23.x)) * r23.x;
        al.w = __expf(lrelu(a23.y + b23.y)) * r23.y;
        lds[256 + t] = al;
        ar = unpack2h(w31);
        float o21 = __expf(lrelu(lo1.z + ar.x)) * ar.y;
        nt_store2(make_float2(o20, o21), &alpha2_2[(base >> 1) + t]);
    }
    __syncthreads();
    // drain: edge v of this block lives at lds[(v&1)*256 + (v>>1)]
    int v0 = t;
    if (base + v0 < Et)
        nt_store4(lds[(v0 & 1) * 256 + (v0 >> 1)], &alpha1[base + v0]);
    int v1 = t + 256;
    if (base + v1 < Et)
        nt_store4(lds[(v1 & 1) * 256 + (v1 >> 1)], &alpha1[base + v1]);
}

extern "C" void kernel_launch(void* const* d_in, const int* in_sizes, int n_in,
                              void* d_out, int out_size, void* d_ws, size_t ws_size,
                              hipStream_t stream)
{
    const float* x   = (const float*)d_in[0];
    const int*   ei  = (const int*)d_in[1];
    const float* W1  = (const float*)d_in[3];
    const float* as1 = (const float*)d_in[4];
    const float* ad1 = (const float*)d_in[5];
    const float* b1  = (const float*)d_in[6];
    const float* W2  = (const float*)d_in[7];
    const float* as2 = (const float*)d_in[8];
    const float* ad2 = (const float*)d_in[9];
    const float* b2  = (const float*)d_in[10];

    const int n  = in_sizes[0] / 2;   // 100000
    const int E  = in_sizes[1] / 2;   // 3200000 (even)
    const int Et = E + n;             // even
    const int nb = (n + BW - 1) >> BSH;  // 196

    char* w = (char*)d_ws;
    float4* ga    = (float4*)w;  w += (size_t)n * sizeof(float4);
    float4* npk   = (float4*)w;  w += (size_t)n * 2 * sizeof(float4);  // 32B/node
    float4* pk2f  = (float4*)w;  w += (size_t)n * sizeof(float4);
    int2*   rowrange = (int2*)w; w += (size_t)n * sizeof(int2);
    int*    sorted   = (int*)w;  w += (size_t)nb * CAP * sizeof(int);
    int*    bucketCursor = (int*)w; w += (size_t)nb * sizeof(int);

    float*  out    = (float*)d_out;
    float4* alpha1 = (float4*)(out + (size_t)n * 2);
    float2* alpha2_2 = (float2*)(alpha1 + (size_t)Et);
    // binned scratch lives in the alpha1 output region, overwritten by k_alpha.
    unsigned int* binned = (unsigned int*)alpha1;

    dim3 blk(256);
    int gn   = (n + 255) / 256;
    int gn8  = (8 * n + 255) / 256;
    int gA   = (Et + 4095) / 4096;
    int gAl  = (Et + 511) / 512;

    k_l1_node  <<<gn,  blk, 0, stream>>>(x, W1, as1, ad1, ga, npk,
                                         bucketCursor, nb, n);
    k_binA     <<<gA,  blk, 0, stream>>>(ei, bucketCursor, binned, E, Et, nb);
    k_binB     <<<nb, dim3(1024), 0, stream>>>(binned, bucketCursor, sorted, rowrange, n, nb);
    k_l1_gather<<<gn8, blk, 0, stream>>>(rowrange, sorted, ga, npk,
                                         W1, b1, W2, as2, ad2, pk2f, n);
    k_l2_gather<<<gn8, blk, 0, stream>>>(rowrange, sorted, pk2f, b2,
                                         npk, out, n);
    k_alpha    <<<gAl, blk, 0, stream>>>(ei, npk,
                                         alpha1, alpha2_2, E, Et);
}

// Round 5
// 271.431 us; speedup vs baseline: 1.0793x; 1.0157x over previous
//
#include <hip/hip_runtime.h>
#include <hip/hip_fp16.h>
#include <math.h>

#define NEG_SLOPE 0.2f
#define BW 512          // bucket node width
#define BSH 9           // log2(BW)
#define CAP 18432       // per-bucket edge capacity (mean ~16.9K)
#define NB_MAX 256

typedef float f4v __attribute__((ext_vector_type(4)));
typedef float f2v __attribute__((ext_vector_type(2)));
typedef int   i2v __attribute__((ext_vector_type(2)));

__device__ __forceinline__ float lrelu(float v) {
    return v > 0.0f ? v : NEG_SLOPE * v;
}
__device__ __forceinline__ float pack2h(float a, float b) {
    __half2 h = __floats2half2_rn(a, b);
    return *reinterpret_cast<float*>(&h);
}
__device__ __forceinline__ float2 unpack2h(float f) {
    __half2 h = *reinterpret_cast<__half2*>(&f);
    return __half22float2(h);
}
__device__ __forceinline__ void nt_store4(float4 v, float4* p) {
    f4v x = {v.x, v.y, v.z, v.w};
    __builtin_nontemporal_store(x, (f4v*)p);
}
__device__ __forceinline__ void nt_store2(float2 v, float2* p) {
    f2v x = {v.x, v.y};
    __builtin_nontemporal_store(x, (f2v*)p);
}

// Unified 32B node record npk[i] (two float4, 64B-line-aligned pairs):
//   lo = npk[2i]   = { as01h, as23h, as2, ad2rs2h }
//   hi = npk[2i+1] = { ad01h, ad23h, rs01h, rs23h }
// k_alpha src side: one dwordx4 (lo) -> 1 line touch.
// k_alpha dst side: hi dwordx4 + lo.w dword -> SAME 64B line -> 1 line touch.
// Table = 3.2MB < 4MB/XCD L2 (R2's 4.8MB split-table variant spilled: +52MB fetch).

// ---------------- KA (merged): node projection + LDS-binned bucket scatter.
// Node projection is independent work interleaved with the long-latency ei
// loads (hides them); bucketCursor zeroing moved to hipMemsetAsync.
__global__ __launch_bounds__(256) void k_binA(
    const float* __restrict__ x, const float* __restrict__ W1,
    const float* __restrict__ asw, const float* __restrict__ adw,
    float4* __restrict__ ga, float4* __restrict__ npk,
    const int* __restrict__ ei, int* __restrict__ bucketCursor,
    unsigned int* __restrict__ binned, int E, int Et, int nb, int n)
{
    __shared__ int cnt[NB_MAX], lscan[NB_MAX], base[NB_MAX], lcur[NB_MAX];
    __shared__ unsigned int staging[4096];
    __shared__ short sbk[4096];
    int t = threadIdx.x;
    int c0 = blockIdx.x * 4096;
    unsigned int ent[16];
    short bb[16];
    #pragma unroll
    for (int k = 0; k < 8; ++k) {
        int e0 = c0 + 2 * (k * 256 + t);
        int s0, d0, s1, d1;
        if (e0 < E) {
            i2v ss = __builtin_nontemporal_load((const i2v*)(ei + e0));
            i2v dd = __builtin_nontemporal_load((const i2v*)(ei + E + e0));
            s0 = ss.x; s1 = ss.y; d0 = dd.x; d1 = dd.y;
        } else { s0 = e0 - E; d0 = s0; s1 = s0 + 1; d1 = s1; }
        bool valid = e0 < Et;   // e0 even, Et even -> e0,e1 valid together
        bb[2 * k]     = valid ? (short)(d0 >> BSH) : (short)(-1);
        bb[2 * k + 1] = valid ? (short)(d1 >> BSH) : (short)(-1);
        ent[2 * k]     = ((unsigned int)s0 << BSH) | (unsigned int)(d0 & (BW - 1));
        ent[2 * k + 1] = ((unsigned int)s1 << BSH) | (unsigned int)(d1 & (BW - 1));
    }
    // node projection (former k_l1_node), independent of the binning state
    int gid = blockIdx.x * 256 + t;
    if (gid < n) {
        float2 xv = ((const float2*)x)[gid];
        float as[4] = {0.f, 0.f, 0.f, 0.f};
        float ad[4] = {0.f, 0.f, 0.f, 0.f};
        #pragma unroll
        for (int j = 0; j < 32; ++j) {
            float h = xv.x * W1[j] + xv.y * W1[32 + j];
            as[j >> 3] += h * asw[j];
            ad[j >> 3] += h * adw[j];
        }
        float p01 = pack2h(as[0], as[1]), p23 = pack2h(as[2], as[3]);
        ga[gid] = make_float4(p01, p23, xv.x, xv.y);
        npk[2 * gid]     = make_float4(p01, p23, 0.f, 0.f);
        npk[2 * gid + 1] = make_float4(pack2h(ad[0], ad[1]), pack2h(ad[2], ad[3]), 0.f, 0.f);
    }
    cnt[t] = 0;
    __syncthreads();
    #pragma unroll
    for (int k = 0; k < 16; ++k)
        if (bb[k] >= 0) atomicAdd(&cnt[bb[k]], 1);
    __syncthreads();
    int c = cnt[t];
    lscan[t] = c;
    __syncthreads();
    // parallel inclusive scan over 256 entries
    for (int off = 1; off < 256; off <<= 1) {
        int v = (t >= off) ? lscan[t - off] : 0;
        __syncthreads();
        lscan[t] += v;
        __syncthreads();
    }
    int tot = lscan[255];
    int ex = lscan[t] - c;
    __syncthreads();
    lscan[t] = ex;          // chunk-local exclusive start of bucket t
    lcur[t] = ex;
    if (t < nb && c > 0) base[t] = atomicAdd(&bucketCursor[t], c);
    __syncthreads();
    #pragma unroll
    for (int k = 0; k < 16; ++k)
        if (bb[k] >= 0) {
            int p = atomicAdd(&lcur[bb[k]], 1);
            staging[p] = ent[k];
            sbk[p] = bb[k];
        }
    __syncthreads();
    for (int j = t; j < tot; j += 256) {
        int lo = sbk[j];
        __builtin_nontemporal_store(staging[j],
            &binned[(size_t)lo * CAP + base[lo] + (j - lscan[lo])]);
    }
}

// ---------------- KB: per-bucket counting sort -> CSR (1024 threads).
__global__ __launch_bounds__(1024) void k_binB(
    const unsigned int* __restrict__ binned, const int* __restrict__ bucketCursor,
    int* __restrict__ sorted, int2* __restrict__ rowrange, int n, int nb)
{
    __shared__ int cnt[BW], cur[BW];
    int t = threadIdx.x;
    int b = blockIdx.x;
    int m = bucketCursor[b];
    size_t base = (size_t)b * CAP;
    int node0 = b << BSH;
    if (t < BW) cnt[t] = 0;
    __syncthreads();
    for (int i = t; i < m; i += 1024)
        atomicAdd(&cnt[binned[base + i] & (BW - 1)], 1);
    __syncthreads();
    int deg = (t < BW) ? cnt[t] : 0;
    for (int off = 1; off < BW; off <<= 1) {
        int v = (t >= off && t < BW) ? cnt[t - off] : 0;
        __syncthreads();
        if (t < BW) cnt[t] += v;
        __syncthreads();
    }
    if (t < BW) {
        int ex = cnt[t] - deg;
        cur[t] = ex;
        int node = node0 + t;
        if (node < n)
            rowrange[node] = make_int2((int)base + ex, (int)base + ex + deg);
    }
    __syncthreads();
    for (int i = t; i < m; i += 1024) {
        unsigned int en = binned[base + i];
        int dl = (int)(en & (BW - 1));
        int p = atomicAdd(&cur[dl], 1);
        sorted[base + p] = (int)(en >> BSH);
    }
}

// ---------------- K5: CSR layer-1 gather, 8 lanes per dst row + L2 prep.
__global__ __launch_bounds__(256) void k_l1_gather(
    const int2* __restrict__ rowrange, const int* __restrict__ sorted,
    const float4* __restrict__ ga, float4* __restrict__ npk,
    const float* __restrict__ W1, const float* __restrict__ b1,
    const float* __restrict__ W2,
    const float* __restrict__ asw2, const float* __restrict__ adw2,
    float4* __restrict__ pk2f, int n)
{
    int t = blockIdx.x * blockDim.x + threadIdx.x;
    int d = t >> 3, q = t & 7;
    if (d >= n) return;
    int2 rr = rowrange[d];
    int beg = rr.x, end = rr.y;
    float2 adp = *(const float2*)&npk[2 * d + 1];   // {ad01h, ad23h}
    float2 ad01 = unpack2h(adp.x), ad23 = unpack2h(adp.y);
    float see[4] = {0.f, 0.f, 0.f, 0.f};
    float sx0[4] = {0.f, 0.f, 0.f, 0.f};
    float sx1[4] = {0.f, 0.f, 0.f, 0.f};
    int i = beg + q;
    for (; i + 8 < end; i += 16) {
        int s0 = sorted[i], s1 = sorted[i + 8];
        float4 v0 = ga[s0], v1 = ga[s1];
        #pragma unroll
        for (int k = 0; k < 2; ++k) {
            float4 v = k ? v1 : v0;
            float2 a01 = unpack2h(v.x), a23 = unpack2h(v.y);
            float e0 = __expf(lrelu(a01.x + ad01.x));
            float e1 = __expf(lrelu(a01.y + ad01.y));
            float e2 = __expf(lrelu(a23.x + ad23.x));
            float e3 = __expf(lrelu(a23.y + ad23.y));
            see[0] += e0; sx0[0] += e0 * v.z; sx1[0] += e0 * v.w;
            see[1] += e1; sx0[1] += e1 * v.z; sx1[1] += e1 * v.w;
            see[2] += e2; sx0[2] += e2 * v.z; sx1[2] += e2 * v.w;
            see[3] += e3; sx0[3] += e3 * v.z; sx1[3] += e3 * v.w;
        }
    }
    for (; i < end; i += 8) {
        float4 v = ga[sorted[i]];
        float2 a01 = unpack2h(v.x), a23 = unpack2h(v.y);
        float e0 = __expf(lrelu(a01.x + ad01.x));
        float e1 = __expf(lrelu(a01.y + ad01.y));
        float e2 = __expf(lrelu(a23.x + ad23.x));
        float e3 = __expf(lrelu(a23.y + ad23.y));
        see[0] += e0; sx0[0] += e0 * v.z; sx1[0] += e0 * v.w;
        see[1] += e1; sx0[1] += e1 * v.z; sx1[1] += e1 * v.w;
        see[2] += e2; sx0[2] += e2 * v.z; sx1[2] += e2 * v.w;
        see[3] += e3; sx0[3] += e3 * v.z; sx1[3] += e3 * v.w;
    }
    // reduce across the 8-lane group
    #pragma unroll
    for (int h = 0; h < 4; ++h) {
        see[h] += __shfl_xor(see[h], 1);
        sx0[h] += __shfl_xor(sx0[h], 1);
        sx1[h] += __shfl_xor(sx1[h], 1);
        see[h] += __shfl_xor(see[h], 2);
        sx0[h] += __shfl_xor(sx0[h], 2);
        sx1[h] += __shfl_xor(sx1[h], 2);
        see[h] += __shfl_xor(see[h], 4);
        sx0[h] += __shfl_xor(sx0[h], 4);
        sx1[h] += __shfl_xor(sx1[h], 4);
    }
    if (q) return;
    float rs[4];
    #pragma unroll
    for (int h = 0; h < 4; ++h) rs[h] = 1.0f / (see[h] + 1e-16f);
    // hi words 2,3 = {rs01h, rs23h}
    ((float2*)&npk[2 * d + 1])[1] = make_float2(pack2h(rs[0], rs[1]), pack2h(rs[2], rs[3]));
    float h20 = 0.f, h21 = 0.f;
    #pragma unroll
    for (int j = 0; j < 32; ++j) {
        int h = j >> 3;
        float num = W1[j] * sx0[h] + W1[32 + j] * sx1[h];
        float o = num * rs[h] + b1[j];
        float he = o > 0.f ? o : expm1f(o);
        h20 += he * W2[2 * j];
        h21 += he * W2[2 * j + 1];
    }
    float as2 = h20 * asw2[0] + h21 * asw2[1];
    float ad2 = h20 * adw2[0] + h21 * adw2[1];
    pk2f[d] = make_float4(as2, h20, h21, ad2);
    ((float*)&npk[2 * d])[2] = as2;                      // lo.z
    ((__half*)&npk[2 * d])[6] = __float2half(ad2);       // lo.w low half
}

// ---------------- K6: CSR layer-2 gather, 8 lanes per dst row + epilogue.
__global__ __launch_bounds__(256) void k_l2_gather(
    const int2* __restrict__ rowrange, const int* __restrict__ sorted,
    const float4* __restrict__ pk2f, const float* __restrict__ b2,
    float4* __restrict__ npk, float* __restrict__ out, int n)
{
    int t = blockIdx.x * blockDim.x + threadIdx.x;
    int d = t >> 3, q = t & 7;
    if (d >= n) return;
    int2 rr = rowrange[d];
    int beg = rr.x, end = rr.y;
    float ad2 = pk2f[d].w;
    float se = 0.f, a0 = 0.f, a1 = 0.f;
    int i = beg + q;
    for (; i + 8 < end; i += 16) {
        int s0 = sorted[i], s1 = sorted[i + 8];
        float4 p0 = pk2f[s0], p1 = pk2f[s1];
        float e0 = __expf(lrelu(p0.x + ad2));
        float e1 = __expf(lrelu(p1.x + ad2));
        se += e0 + e1;
        a0 += e0 * p0.y + e1 * p1.y;
        a1 += e0 * p0.z + e1 * p1.z;
    }
    for (; i < end; i += 8) {
        float4 p = pk2f[sorted[i]];
        float ee = __expf(lrelu(p.x + ad2));
        se += ee; a0 += ee * p.y; a1 += ee * p.z;
    }
    se += __shfl_xor(se, 1); a0 += __shfl_xor(a0, 1); a1 += __shfl_xor(a1, 1);
    se += __shfl_xor(se, 2); a0 += __shfl_xor(a0, 2); a1 += __shfl_xor(a1, 2);
    se += __shfl_xor(se, 4); a0 += __shfl_xor(a0, 4); a1 += __shfl_xor(a1, 4);
    if (q) return;
    float rs2 = 1.0f / (se + 1e-16f);
    ((__half*)&npk[2 * d])[7] = __float2half(rs2);   // lo.w high half
    ((float2*)out)[d] = make_float2(a0 * rs2 + b2[0], a1 * rs2 + b2[1]);
}

// ---------------- K7: merged COO alpha pass, 2 ADJACENT edges/thread.
// WAVE-LOCAL LDS retile: each wave owns 128 edges and a private 2KB LDS
// region; staging writes and drain reads are same-wave (wave64 lockstep +
// compiler lgkmcnt ordering) -> NO __syncthreads. Removes the block-wide
// convoy so one wave's gathers overlap another's NT-store drain.
// 2 random line-touches/edge (npk lo for src; hi + lo.w, same 64B line,
// for dst). alpha1 drained as lane-contiguous full-line NT stores.
__global__ __launch_bounds__(256) void k_alpha(
    const int* __restrict__ ei, const float4* __restrict__ npk,
    float4* __restrict__ alpha1, float2* __restrict__ alpha2_2, int E, int Et)
{
    __shared__ float4 lds[512];       // 4 waves x 128 slots
    int t = threadIdx.x;
    int w = t >> 6, l = t & 63;
    int wbase = blockIdx.x * 512 + w * 128;
    float4* wlds = &lds[w * 128];
    int e0 = wbase + 2 * l;
    if (e0 < Et) {
        int s0, d0, s1, d1;
        if (e0 < E) {
            i2v ss = __builtin_nontemporal_load((const i2v*)(ei + e0));
            i2v dd = __builtin_nontemporal_load((const i2v*)(ei + E + e0));
            s0 = ss.x; s1 = ss.y; d0 = dd.x; d1 = dd.y;
        } else {
            s0 = e0 - E; d0 = s0; s1 = s0 + 1; d1 = s1;
        }
        float4 lo0 = npk[2 * s0], lo1 = npk[2 * s1];          // src: 1 line
        float4 hi0 = npk[2 * d0 + 1], hi1 = npk[2 * d1 + 1];  // dst: same line as
        float  w30 = ((const float*)npk)[8 * d0 + 3];         //      lo.w below
        float  w31 = ((const float*)npk)[8 * d1 + 3];

        float2 a01, a23, b01, b23, r01, r23, ar;
        float4 al;
        // edge 0 -> local slot A(2l) = l
        a01 = unpack2h(lo0.x); a23 = unpack2h(lo0.y);
        b01 = unpack2h(hi0.x); b23 = unpack2h(hi0.y);
        r01 = unpack2h(hi0.z); r23 = unpack2h(hi0.w);
        al.x = __expf(lrelu(a01.x + b01.x)) * r01.x;
        al.y = __expf(lrelu(a01.y + b01.y)) * r01.y;
        al.z = __expf(lrelu(a23.x + b23.x)) * r23.x;
        al.w = __expf(lrelu(a23.y + b23.y)) * r23.y;
        wlds[l] = al;
        ar = unpack2h(w30);
        float o20 = __expf(lrelu(lo0.z + ar.x)) * ar.y;
        // edge 1 -> local slot A(2l+1) = 64 + l
        a01 = unpack2h(lo1.x); a23 = unpack2h(lo1.y);
        b01 = unpack2h(hi1.x); b23 = unpack2h(hi1.y);
        r01 = unpack2h(hi1.z); r23 = unpack2h(hi1.w);
        al.x = __expf(lrelu(a01.x + b01.x)) * r01.x;
        al.y = __expf(lrelu(a01.y + b01.y)) * r01.y;
        al.z = __expf(lrelu(a23.x + b23.x)) * r23.x;
        al.w = __expf(lrelu(a23.y + b23.y)) * r23.y;
        wlds[64 + l] = al;
        ar = unpack2h(w31);
        float o21 = __expf(lrelu(lo1.z + ar.x)) * ar.y;
        nt_store2(make_float2(o20, o21), &alpha2_2[(wbase >> 1) + l]);
    }
    // wave-local drain (slot of local edge v: (v&1)*64 + (v>>1))
    int v0 = wbase + l;
    if (v0 < Et)
        nt_store4(wlds[(l & 1) * 64 + (l >> 1)], &alpha1[v0]);
    int v1 = wbase + 64 + l;
    if (v1 < Et)
        nt_store4(wlds[(l & 1) * 64 + 32 + (l >> 1)], &alpha1[v1]);
}

extern "C" void kernel_launch(void* const* d_in, const int* in_sizes, int n_in,
                              void* d_out, int out_size, void* d_ws, size_t ws_size,
                              hipStream_t stream)
{
    const float* x   = (const float*)d_in[0];
    const int*   ei  = (const int*)d_in[1];
    const float* W1  = (const float*)d_in[3];
    const float* as1 = (const float*)d_in[4];
    const float* ad1 = (const float*)d_in[5];
    const float* b1  = (const float*)d_in[6];
    const float* W2  = (const float*)d_in[7];
    const float* as2 = (const float*)d_in[8];
    const float* ad2 = (const float*)d_in[9];
    const float* b2  = (const float*)d_in[10];

    const int n  = in_sizes[0] / 2;   // 100000
    const int E  = in_sizes[1] / 2;   // 3200000 (even)
    const int Et = E + n;             // even
    const int nb = (n + BW - 1) >> BSH;  // 196

    char* w = (char*)d_ws;
    float4* ga    = (float4*)w;  w += (size_t)n * sizeof(float4);
    float4* npk   = (float4*)w;  w += (size_t)n * 2 * sizeof(float4);  // 32B/node
    float4* pk2f  = (float4*)w;  w += (size_t)n * sizeof(float4);
    int2*   rowrange = (int2*)w; w += (size_t)n * sizeof(int2);
    int*    sorted   = (int*)w;  w += (size_t)nb * CAP * sizeof(int);
    int*    bucketCursor = (int*)w; w += (size_t)nb * sizeof(int);

    float*  out    = (float*)d_out;
    float4* alpha1 = (float4*)(out + (size_t)n * 2);
    float2* alpha2_2 = (float2*)(alpha1 + (size_t)Et);
    // binned scratch lives in the alpha1 output region, overwritten by k_alpha.
    unsigned int* binned = (unsigned int*)alpha1;

    dim3 blk(256);
    int gn8  = (8 * n + 255) / 256;
    int gA   = (Et + 4095) / 4096;     // 806 blocks >= ceil(n/256)=391 for node work
    int gAl  = (Et + 511) / 512;

    hipMemsetAsync(bucketCursor, 0, nb * sizeof(int), stream);
    k_binA     <<<gA,  blk, 0, stream>>>(x, W1, as1, ad1, ga, npk,
                                         ei, bucketCursor, binned, E, Et, nb, n);
    k_binB     <<<nb, dim3(1024), 0, stream>>>(binned, bucketCursor, sorted, rowrange, n, nb);
    k_l1_gather<<<gn8, blk, 0, stream>>>(rowrange, sorted, ga, npk,
                                         W1, b1, W2, as2, ad2, pk2f, n);
    k_l2_gather<<<gn8, blk, 0, stream>>>(rowrange, sorted, pk2f, b2,
                                         npk, out, n);
    k_alpha    <<<gAl, blk, 0, stream>>>(ei, npk,
                                         alpha1, alpha2_2, E, Et);
}

// Round 6
// 271.030 us; speedup vs baseline: 1.0809x; 1.0015x over previous
//
#include <hip/hip_runtime.h>
#include <hip/hip_fp16.h>
#include <math.h>

#define NEG_SLOPE 0.2f
#define BW 512          // bucket node width
#define BSH 9           // log2(BW)
#define CAP 18432       // per-bucket edge capacity (mean ~16.9K, max ~17.4K)
#define NB_MAX 256

typedef float f4v __attribute__((ext_vector_type(4)));
typedef float f2v __attribute__((ext_vector_type(2)));
typedef int   i2v __attribute__((ext_vector_type(2)));
typedef int   i4v __attribute__((ext_vector_type(4)));

__device__ __forceinline__ float lrelu(float v) {
    return v > 0.0f ? v : NEG_SLOPE * v;
}
__device__ __forceinline__ float pack2h(float a, float b) {
    __half2 h = __floats2half2_rn(a, b);
    return *reinterpret_cast<float*>(&h);
}
__device__ __forceinline__ float2 unpack2h(float f) {
    __half2 h = *reinterpret_cast<__half2*>(&f);
    return __half22float2(h);
}
__device__ __forceinline__ void nt_store4(float4 v, float4* p) {
    f4v x = {v.x, v.y, v.z, v.w};
    __builtin_nontemporal_store(x, (f4v*)p);
}

// Unified 32B node record npk[i] (two float4, 64B-line-aligned pairs):
//   lo = npk[2i]   = { as01h, as23h, as2, ad2rs2h }
//   hi = npk[2i+1] = { ad01h, ad23h, rs01h, rs23h }
// k_alpha src side: one dwordx4 (lo) -> 1 random line touch.
// k_alpha dst side: hi dwordx4 + lo.w dword -> SAME 64B line -> 1 line touch.
// Table = 3.2MB < 4MB/XCD L2.

// ---------------- KA (merged): node projection + LDS-binned bucket scatter.
__global__ __launch_bounds__(256) void k_binA(
    const float* __restrict__ x, const float* __restrict__ W1,
    const float* __restrict__ asw, const float* __restrict__ adw,
    float4* __restrict__ ga, float4* __restrict__ npk,
    const int* __restrict__ ei, int* __restrict__ bucketCursor,
    unsigned int* __restrict__ binned, int E, int Et, int nb, int n)
{
    __shared__ int cnt[NB_MAX], lscan[NB_MAX], base[NB_MAX], lcur[NB_MAX];
    __shared__ unsigned int staging[4096];
    __shared__ short sbk[4096];
    int t = threadIdx.x;
    int c0 = blockIdx.x * 4096;
    unsigned int ent[16];
    short bb[16];
    #pragma unroll
    for (int k = 0; k < 8; ++k) {
        int e0 = c0 + 2 * (k * 256 + t);
        int s0, d0, s1, d1;
        if (e0 < E) {
            i2v ss = __builtin_nontemporal_load((const i2v*)(ei + e0));
            i2v dd = __builtin_nontemporal_load((const i2v*)(ei + E + e0));
            s0 = ss.x; s1 = ss.y; d0 = dd.x; d1 = dd.y;
        } else { s0 = e0 - E; d0 = s0; s1 = s0 + 1; d1 = s1; }
        bool valid = e0 < Et;   // e0 even, Et even -> e0,e1 valid together
        bb[2 * k]     = valid ? (short)(d0 >> BSH) : (short)(-1);
        bb[2 * k + 1] = valid ? (short)(d1 >> BSH) : (short)(-1);
        ent[2 * k]     = ((unsigned int)s0 << BSH) | (unsigned int)(d0 & (BW - 1));
        ent[2 * k + 1] = ((unsigned int)s1 << BSH) | (unsigned int)(d1 & (BW - 1));
    }
    // node projection (independent work hiding ei latency)
    int gid = blockIdx.x * 256 + t;
    if (gid < n) {
        float2 xv = ((const float2*)x)[gid];
        float as[4] = {0.f, 0.f, 0.f, 0.f};
        float ad[4] = {0.f, 0.f, 0.f, 0.f};
        #pragma unroll
        for (int j = 0; j < 32; ++j) {
            float h = xv.x * W1[j] + xv.y * W1[32 + j];
            as[j >> 3] += h * asw[j];
            ad[j >> 3] += h * adw[j];
        }
        float p01 = pack2h(as[0], as[1]), p23 = pack2h(as[2], as[3]);
        ga[gid] = make_float4(p01, p23, xv.x, xv.y);
        npk[2 * gid]     = make_float4(p01, p23, 0.f, 0.f);
        npk[2 * gid + 1] = make_float4(pack2h(ad[0], ad[1]), pack2h(ad[2], ad[3]), 0.f, 0.f);
    }
    cnt[t] = 0;
    __syncthreads();
    #pragma unroll
    for (int k = 0; k < 16; ++k)
        if (bb[k] >= 0) atomicAdd(&cnt[bb[k]], 1);
    __syncthreads();
    int c = cnt[t];
    lscan[t] = c;
    __syncthreads();
    // parallel inclusive scan over 256 entries
    for (int off = 1; off < 256; off <<= 1) {
        int v = (t >= off) ? lscan[t - off] : 0;
        __syncthreads();
        lscan[t] += v;
        __syncthreads();
    }
    int tot = lscan[255];
    int ex = lscan[t] - c;
    __syncthreads();
    lscan[t] = ex;          // chunk-local exclusive start of bucket t
    lcur[t] = ex;
    if (t < nb && c > 0) base[t] = atomicAdd(&bucketCursor[t], c);
    __syncthreads();
    #pragma unroll
    for (int k = 0; k < 16; ++k)
        if (bb[k] >= 0) {
            int p = atomicAdd(&lcur[bb[k]], 1);
            staging[p] = ent[k];
            sbk[p] = bb[k];
        }
    __syncthreads();
    for (int j = t; j < tot; j += 256) {
        int lo = sbk[j];
        __builtin_nontemporal_store(staging[j],
            &binned[(size_t)lo * CAP + base[lo] + (j - lscan[lo])]);
    }
}

// ---------------- KB: per-bucket counting sort -> CSR (1024 threads).
// Whole bucket staged in LDS (73.7KB; gfx950 allows >=128KB/WG): single
// global read (fused with counting), placement pass reads LDS.
__global__ __launch_bounds__(1024) void k_binB(
    const unsigned int* __restrict__ binned, const int* __restrict__ bucketCursor,
    int* __restrict__ sorted, int2* __restrict__ rowrange, int n, int nb)
{
    __shared__ int cnt[BW], cur[BW];
    __shared__ unsigned int stage[CAP];
    int t = threadIdx.x;
    int b = blockIdx.x;
    int m = bucketCursor[b];
    size_t base = (size_t)b * CAP;
    int node0 = b << BSH;
    if (t < BW) cnt[t] = 0;
    __syncthreads();
    for (int i = t; i < m; i += 1024) {
        unsigned int en = __builtin_nontemporal_load(&binned[base + i]);
        stage[i] = en;
        atomicAdd(&cnt[en & (BW - 1)], 1);
    }
    __syncthreads();
    int deg = (t < BW) ? cnt[t] : 0;
    for (int off = 1; off < BW; off <<= 1) {
        int v = (t >= off && t < BW) ? cnt[t - off] : 0;
        __syncthreads();
        if (t < BW) cnt[t] += v;
        __syncthreads();
    }
    if (t < BW) {
        int ex = cnt[t] - deg;
        cur[t] = ex;
        int node = node0 + t;
        if (node < n)
            rowrange[node] = make_int2((int)base + ex, (int)base + ex + deg);
    }
    __syncthreads();
    for (int i = t; i < m; i += 1024) {
        unsigned int en = stage[i];
        int dl = (int)(en & (BW - 1));
        int p = atomicAdd(&cur[dl], 1);
        sorted[base + p] = (int)(en >> BSH);
    }
}

// ---------------- K5: CSR layer-1 gather, 8 lanes per dst row + L2 prep.
__global__ __launch_bounds__(256) void k_l1_gather(
    const int2* __restrict__ rowrange, const int* __restrict__ sorted,
    const float4* __restrict__ ga, float4* __restrict__ npk,
    const float* __restrict__ W1, const float* __restrict__ b1,
    const float* __restrict__ W2,
    const float* __restrict__ asw2, const float* __restrict__ adw2,
    float4* __restrict__ pk2f, int n)
{
    int t = blockIdx.x * blockDim.x + threadIdx.x;
    int d = t >> 3, q = t & 7;
    if (d >= n) return;
    int2 rr = rowrange[d];
    int beg = rr.x, end = rr.y;
    float2 adp = *(const float2*)&npk[2 * d + 1];   // {ad01h, ad23h}
    float2 ad01 = unpack2h(adp.x), ad23 = unpack2h(adp.y);
    float see[4] = {0.f, 0.f, 0.f, 0.f};
    float sx0[4] = {0.f, 0.f, 0.f, 0.f};
    float sx1[4] = {0.f, 0.f, 0.f, 0.f};
    int i = beg + q;
    for (; i + 8 < end; i += 16) {
        int s0 = sorted[i], s1 = sorted[i + 8];
        float4 v0 = ga[s0], v1 = ga[s1];
        #pragma unroll
        for (int k = 0; k < 2; ++k) {
            float4 v = k ? v1 : v0;
            float2 a01 = unpack2h(v.x), a23 = unpack2h(v.y);
            float e0 = __expf(lrelu(a01.x + ad01.x));
            float e1 = __expf(lrelu(a01.y + ad01.y));
            float e2 = __expf(lrelu(a23.x + ad23.x));
            float e3 = __expf(lrelu(a23.y + ad23.y));
            see[0] += e0; sx0[0] += e0 * v.z; sx1[0] += e0 * v.w;
            see[1] += e1; sx0[1] += e1 * v.z; sx1[1] += e1 * v.w;
            see[2] += e2; sx0[2] += e2 * v.z; sx1[2] += e2 * v.w;
            see[3] += e3; sx0[3] += e3 * v.z; sx1[3] += e3 * v.w;
        }
    }
    for (; i < end; i += 8) {
        float4 v = ga[sorted[i]];
        float2 a01 = unpack2h(v.x), a23 = unpack2h(v.y);
        float e0 = __expf(lrelu(a01.x + ad01.x));
        float e1 = __expf(lrelu(a01.y + ad01.y));
        float e2 = __expf(lrelu(a23.x + ad23.x));
        float e3 = __expf(lrelu(a23.y + ad23.y));
        see[0] += e0; sx0[0] += e0 * v.z; sx1[0] += e0 * v.w;
        see[1] += e1; sx0[1] += e1 * v.z; sx1[1] += e1 * v.w;
        see[2] += e2; sx0[2] += e2 * v.z; sx1[2] += e2 * v.w;
        see[3] += e3; sx0[3] += e3 * v.z; sx1[3] += e3 * v.w;
    }
    // reduce across the 8-lane group
    #pragma unroll
    for (int h = 0; h < 4; ++h) {
        see[h] += __shfl_xor(see[h], 1);
        sx0[h] += __shfl_xor(sx0[h], 1);
        sx1[h] += __shfl_xor(sx1[h], 1);
        see[h] += __shfl_xor(see[h], 2);
        sx0[h] += __shfl_xor(sx0[h], 2);
        sx1[h] += __shfl_xor(sx1[h], 2);
        see[h] += __shfl_xor(see[h], 4);
        sx0[h] += __shfl_xor(sx0[h], 4);
        sx1[h] += __shfl_xor(sx1[h], 4);
    }
    if (q) return;
    float rs[4];
    #pragma unroll
    for (int h = 0; h < 4; ++h) rs[h] = 1.0f / (see[h] + 1e-16f);
    // hi words 2,3 = {rs01h, rs23h}
    ((float2*)&npk[2 * d + 1])[1] = make_float2(pack2h(rs[0], rs[1]), pack2h(rs[2], rs[3]));
    float h20 = 0.f, h21 = 0.f;
    #pragma unroll
    for (int j = 0; j < 32; ++j) {
        int h = j >> 3;
        float num = W1[j] * sx0[h] + W1[32 + j] * sx1[h];
        float o = num * rs[h] + b1[j];
        float he = o > 0.f ? o : expm1f(o);
        h20 += he * W2[2 * j];
        h21 += he * W2[2 * j + 1];
    }
    float as2 = h20 * asw2[0] + h21 * asw2[1];
    float ad2 = h20 * adw2[0] + h21 * adw2[1];
    pk2f[d] = make_float4(as2, h20, h21, ad2);
    ((float*)&npk[2 * d])[2] = as2;                      // lo.z
    ((__half*)&npk[2 * d])[6] = __float2half(ad2);       // lo.w low half
}

// ---------------- K6: CSR layer-2 gather, 8 lanes per dst row + epilogue.
__global__ __launch_bounds__(256) void k_l2_gather(
    const int2* __restrict__ rowrange, const int* __restrict__ sorted,
    const float4* __restrict__ pk2f, const float* __restrict__ b2,
    float4* __restrict__ npk, float* __restrict__ out, int n)
{
    int t = blockIdx.x * blockDim.x + threadIdx.x;
    int d = t >> 3, q = t & 7;
    if (d >= n) return;
    int2 rr = rowrange[d];
    int beg = rr.x, end = rr.y;
    float ad2 = pk2f[d].w;
    float se = 0.f, a0 = 0.f, a1 = 0.f;
    int i = beg + q;
    for (; i + 8 < end; i += 16) {
        int s0 = sorted[i], s1 = sorted[i + 8];
        float4 p0 = pk2f[s0], p1 = pk2f[s1];
        float e0 = __expf(lrelu(p0.x + ad2));
        float e1 = __expf(lrelu(p1.x + ad2));
        se += e0 + e1;
        a0 += e0 * p0.y + e1 * p1.y;
        a1 += e0 * p0.z + e1 * p1.z;
    }
    for (; i < end; i += 8) {
        float4 p = pk2f[sorted[i]];
        float ee = __expf(lrelu(p.x + ad2));
        se += ee; a0 += ee * p.y; a1 += ee * p.z;
    }
    se += __shfl_xor(se, 1); a0 += __shfl_xor(a0, 1); a1 += __shfl_xor(a1, 1);
    se += __shfl_xor(se, 2); a0 += __shfl_xor(a0, 2); a1 += __shfl_xor(a1, 2);
    se += __shfl_xor(se, 4); a0 += __shfl_xor(a0, 4); a1 += __shfl_xor(a1, 4);
    if (q) return;
    float rs2 = 1.0f / (se + 1e-16f);
    ((__half*)&npk[2 * d])[7] = __float2half(rs2);   // lo.w high half
    ((float2*)out)[d] = make_float2(a0 * rs2 + b2[0], a1 * rs2 + b2[1]);
}

// ---------------- K7: merged COO alpha pass, 4 ADJACENT edges/thread.
// Deep MLP: one int4 per ei stream, then ALL 12 gathers (4x lo, 4x hi,
// 4x lo.w — hi & lo.w share a 64B line) issued before any use. The old
// 2-edge version compiled to 16 VGPRs -> loads serialized; this forces
// the results live simultaneously (~80 VGPRs, still >=16 waves/CU).
// Wave-local LDS retile (no barrier): write wlds[k*64+l], drain slot for
// edge v = r*64+l is (l&3)*64 + 16r + (l>>2)  [v&3 = l&3, v>>2 = 16r+(l>>2)].
// alpha2: one nt_store4 per thread (Et, E both divisible by 4).
__global__ __launch_bounds__(256) void k_alpha(
    const int* __restrict__ ei, const float4* __restrict__ npk,
    float4* __restrict__ alpha1, float4* __restrict__ alpha2_4, int E, int Et)
{
    __shared__ float4 lds[1024];      // 4 waves x 256 slots (16KB)
    int t = threadIdx.x;
    int w = t >> 6, l = t & 63;
    int wbase = blockIdx.x * 1024 + w * 256;
    float4* wlds = &lds[w * 256];
    int e0 = wbase + 4 * l;
    if (e0 < Et) {
        int s[4], d[4];
        if (e0 < E) {
            i4v ss = __builtin_nontemporal_load((const i4v*)(ei + e0));
            i4v dd = __builtin_nontemporal_load((const i4v*)(ei + E + e0));
            s[0] = ss.x; s[1] = ss.y; s[2] = ss.z; s[3] = ss.w;
            d[0] = dd.x; d[1] = dd.y; d[2] = dd.z; d[3] = dd.w;
        } else {
            #pragma unroll
            for (int k = 0; k < 4; ++k) { s[k] = e0 - E + k; d[k] = s[k]; }
        }
        float4 lo[4], hi[4];
        float  w3[4];
        #pragma unroll
        for (int k = 0; k < 4; ++k) {
            lo[k] = npk[2 * s[k]];
            hi[k] = npk[2 * d[k] + 1];
            w3[k] = ((const float*)npk)[8 * d[k] + 3];
        }
        float o2[4];
        #pragma unroll
        for (int k = 0; k < 4; ++k) {
            float2 a01 = unpack2h(lo[k].x), a23 = unpack2h(lo[k].y);
            float2 b01 = unpack2h(hi[k].x), b23 = unpack2h(hi[k].y);
            float2 r01 = unpack2h(hi[k].z), r23 = unpack2h(hi[k].w);
            float4 al;
            al.x = __expf(lrelu(a01.x + b01.x)) * r01.x;
            al.y = __expf(lrelu(a01.y + b01.y)) * r01.y;
            al.z = __expf(lrelu(a23.x + b23.x)) * r23.x;
            al.w = __expf(lrelu(a23.y + b23.y)) * r23.y;
            wlds[k * 64 + l] = al;
            float2 ar = unpack2h(w3[k]);
            o2[k] = __expf(lrelu(lo[k].z + ar.x)) * ar.y;
        }
        nt_store4(make_float4(o2[0], o2[1], o2[2], o2[3]), &alpha2_4[e0 >> 2]);
    }
    // wave-local drain: 4 rounds of lane-contiguous full-line NT stores
    #pragma unroll
    for (int r = 0; r < 4; ++r) {
        int v = wbase + r * 64 + l;
        if (v < Et)
            nt_store4(wlds[(l & 3) * 64 + 16 * r + (l >> 2)], &alpha1[v]);
    }
}

extern "C" void kernel_launch(void* const* d_in, const int* in_sizes, int n_in,
                              void* d_out, int out_size, void* d_ws, size_t ws_size,
                              hipStream_t stream)
{
    const float* x   = (const float*)d_in[0];
    const int*   ei  = (const int*)d_in[1];
    const float* W1  = (const float*)d_in[3];
    const float* as1 = (const float*)d_in[4];
    const float* ad1 = (const float*)d_in[5];
    const float* b1  = (const float*)d_in[6];
    const float* W2  = (const float*)d_in[7];
    const float* as2 = (const float*)d_in[8];
    const float* ad2 = (const float*)d_in[9];
    const float* b2  = (const float*)d_in[10];

    const int n  = in_sizes[0] / 2;   // 100000 (divisible by 4)
    const int E  = in_sizes[1] / 2;   // 3200000 (divisible by 4)
    const int Et = E + n;             // divisible by 4
    const int nb = (n + BW - 1) >> BSH;  // 196

    char* w = (char*)d_ws;
    float4* ga    = (float4*)w;  w += (size_t)n * sizeof(float4);
    float4* npk   = (float4*)w;  w += (size_t)n * 2 * sizeof(float4);  // 32B/node
    float4* pk2f  = (float4*)w;  w += (size_t)n * sizeof(float4);
    int2*   rowrange = (int2*)w; w += (size_t)n * sizeof(int2);
    int*    sorted   = (int*)w;  w += (size_t)nb * CAP * sizeof(int);
    int*    bucketCursor = (int*)w; w += (size_t)nb * sizeof(int);

    float*  out    = (float*)d_out;
    float4* alpha1 = (float4*)(out + (size_t)n * 2);
    float4* alpha2_4 = (float4*)(alpha1 + (size_t)Et);
    // binned scratch lives in the alpha1 output region, overwritten by k_alpha.
    unsigned int* binned = (unsigned int*)alpha1;

    dim3 blk(256);
    int gn8  = (8 * n + 255) / 256;
    int gA   = (Et + 4095) / 4096;     // 806 blocks >= ceil(n/256)=391 for node work
    int gAl  = (Et + 1023) / 1024;

    hipMemsetAsync(bucketCursor, 0, nb * sizeof(int), stream);
    k_binA     <<<gA,  blk, 0, stream>>>(x, W1, as1, ad1, ga, npk,
                                         ei, bucketCursor, binned, E, Et, nb, n);
    k_binB     <<<nb, dim3(1024), 0, stream>>>(binned, bucketCursor, sorted, rowrange, n, nb);
    k_l1_gather<<<gn8, blk, 0, stream>>>(rowrange, sorted, ga, npk,
                                         W1, b1, W2, as2, ad2, pk2f, n);
    k_l2_gather<<<gn8, blk, 0, stream>>>(rowrange, sorted, pk2f, b2,
                                         npk, out, n);
    k_alpha    <<<gAl, blk, 0, stream>>>(ei, npk,
                                         alpha1, alpha2_4, E, Et);
}